// Round 4
// baseline (769.377 us; speedup 1.0000x reference)
//
#include <hip/hip_runtime.h>
#include <hip/hip_bf16.h>

// Problem constants
#define BT 32768      // B*T = 64*512
#define TSTEPS 512
#define NBATCH 64
#define KDIM 512      // IN_DIM
#define NPAD 208      // P row stride
#define NW 256        // Wc padded cols

#define L2E 1.4426950408889634f
#define T2E 2.8853900817779268f

__device__ __forceinline__ float rl(float v, int lane) {
    return __int_as_float(__builtin_amdgcn_readlane(__float_as_int(v), lane));
}
__device__ __forceinline__ float bperm(int byteidx, float v) {
    return __int_as_float(__builtin_amdgcn_ds_bpermute(byteidx, __float_as_int(v)));
}
// unified activation: a * rcp(1 + exp2(s*x + sc)) + b
__device__ __forceinline__ float actf(float x, float s, float sc, float a, float b) {
    float e = exp2f(fmaf(s, x, sc));
    return fmaf(a, __builtin_amdgcn_rcpf(1.f + e), b);
}

// P column layout (dot-major):
//   cols 0..127   = z dots 0..127            (dot d = gate*33 + neuron)
//   cols 128..191 = layer0 dots 0..63        (dot e = m*18 + i)
//   cols 192..195 = z dots 128..131
//   cols 196..203 = layer0 dots 64..71
//   cols 204..207 = pad (zeros)
__device__ __forceinline__ int permpos(int o) {
    if (o < 128) return o;
    if (o < 132) return o + 64;
    if (o < 196) return o - 4;
    return o;
}

// ---------------------------------------------------------------------------
// Kernel 1: fold fc1 into the stacked scan-input projection (permuted cols).
// ---------------------------------------------------------------------------
__global__ __launch_bounds__(256) void fold_kernel(
    const float* __restrict__ fc1_w, const float* __restrict__ fc1_b,
    const float* __restrict__ lstm_wi, const float* __restrict__ lstm_bi,
    const float* __restrict__ ff1w0, const float* __restrict__ ff2w0,
    const float* __restrict__ taw0, const float* __restrict__ tbw0,
    const float* __restrict__ ff1b0, const float* __restrict__ ff2b0,
    const float* __restrict__ tab0, const float* __restrict__ tbb0,
    const float* __restrict__ mask0,
    float* __restrict__ Wc, float* __restrict__ bc)
{
    const int o = blockIdx.x;
    const int t = threadIdx.x;
    const int p = permpos(o);
    __shared__ float wrow[256];
    __shared__ float red[256];

    float wl = 0.f, b0 = 0.f;
    if (o < 132)      { wl = lstm_wi[o * 256 + t];                         b0 = lstm_bi[o]; }
    else if (o < 150) { int i = o - 132; wl = ff1w0[i * 274 + t] * mask0[i * 274 + t]; b0 = ff1b0[i]; }
    else if (o < 168) { int i = o - 150; wl = ff2w0[i * 274 + t] * mask0[i * 274 + t]; b0 = ff2b0[i]; }
    else if (o < 186) { int i = o - 168; wl = taw0[i * 274 + t];           b0 = tab0[i]; }
    else if (o < 204) { int i = o - 186; wl = tbw0[i * 274 + t];           b0 = tbb0[i]; }
    wrow[t] = wl;
    __syncthreads();

    float acc0 = 0.f, acc1 = 0.f;
    for (int l = 0; l < 256; l++) {
        float w = wrow[l];
        acc0 = fmaf(fc1_w[l * 512 + t], w, acc0);
        acc1 = fmaf(fc1_w[l * 512 + t + 256], w, acc1);
    }
    Wc[(size_t)t * NW + p] = acc0;
    Wc[(size_t)(t + 256) * NW + p] = acc1;

    red[t] = fc1_b[t] * wl;
    __syncthreads();
    for (int s = 128; s > 0; s >>= 1) {
        if (t < s) red[t] += red[t + s];
        __syncthreads();
    }
    if (t == 0) bc[p] = red[0] + b0;
}

// ---------------------------------------------------------------------------
// Kernel 2: P[m][n] = sum_k X[m][k]*Wc[k][n] + bc[n], fp32 LDS-tiled GEMM.
// ---------------------------------------------------------------------------
__global__ __launch_bounds__(256) void gemm_kernel(
    const float* __restrict__ X, const float* __restrict__ Wc,
    const float* __restrict__ bc, float* __restrict__ P)
{
    __shared__ float As[16][68];
    __shared__ float Bs[16][64];
    const int tid = threadIdx.x;
    const int m0 = blockIdx.x * 64;
    const int n0 = blockIdx.y * 64;
    const int lr = tid >> 2;
    const int lc = (tid & 3) << 2;
    const int wr = tid >> 4;
    const int wc = (tid & 15) << 2;
    const int tm = (tid >> 4) << 2;
    const int tn = (tid & 15) << 2;

    float acc[4][4];
#pragma unroll
    for (int i = 0; i < 4; i++)
#pragma unroll
        for (int j = 0; j < 4; j++) acc[i][j] = 0.f;

    for (int k0 = 0; k0 < KDIM; k0 += 16) {
        float4 av = *(const float4*)(X + (size_t)(m0 + lr) * KDIM + k0 + lc);
        float4 bv = *(const float4*)(Wc + (size_t)(k0 + wr) * NW + n0 + wc);
        __syncthreads();
        As[lc + 0][lr] = av.x; As[lc + 1][lr] = av.y;
        As[lc + 2][lr] = av.z; As[lc + 3][lr] = av.w;
        *(float4*)&Bs[wr][wc] = bv;
        __syncthreads();
#pragma unroll
        for (int k = 0; k < 16; k++) {
            float4 a = *(const float4*)&As[k][tm];
            float4 b = *(const float4*)&Bs[k][tn];
            acc[0][0] = fmaf(a.x, b.x, acc[0][0]); acc[0][1] = fmaf(a.x, b.y, acc[0][1]);
            acc[0][2] = fmaf(a.x, b.z, acc[0][2]); acc[0][3] = fmaf(a.x, b.w, acc[0][3]);
            acc[1][0] = fmaf(a.y, b.x, acc[1][0]); acc[1][1] = fmaf(a.y, b.y, acc[1][1]);
            acc[1][2] = fmaf(a.y, b.z, acc[1][2]); acc[1][3] = fmaf(a.y, b.w, acc[1][3]);
            acc[2][0] = fmaf(a.z, b.x, acc[2][0]); acc[2][1] = fmaf(a.z, b.y, acc[2][1]);
            acc[2][2] = fmaf(a.z, b.z, acc[2][2]); acc[2][3] = fmaf(a.z, b.w, acc[2][3]);
            acc[3][0] = fmaf(a.w, b.x, acc[3][0]); acc[3][1] = fmaf(a.w, b.y, acc[3][1]);
            acc[3][2] = fmaf(a.w, b.z, acc[3][2]); acc[3][3] = fmaf(a.w, b.w, acc[3][3]);
        }
    }

    if (n0 + tn < NPAD) {
        float4 bias = *(const float4*)(bc + n0 + tn);
#pragma unroll
        for (int i = 0; i < 4; i++) {
            float4 r;
            r.x = acc[i][0] + bias.x; r.y = acc[i][1] + bias.y;
            r.z = acc[i][2] + bias.z; r.w = acc[i][3] + bias.w;
            *(float4*)(P + (size_t)(m0 + tm + i) * NPAD + n0 + tn) = r;
        }
    }
}

// ---------------------------------------------------------------------------
// Kernel 3: persistent scan, one wave per batch element.
// Register-resident weights trimmed to fit (~180 VGPR): wA/wB/w0A/w1/w2 in
// VGPRs; the duplicated wC (4 rows) and w0B (8 rows) live transposed in LDS
// (broadcast-class ds_read_b32, constant offsets). 2-step-deep P prefetch.
// ---------------------------------------------------------------------------
__global__ __launch_bounds__(64, 1) void scan_kernel(
    const float* __restrict__ P, const float* __restrict__ lstm_wh,
    const float* __restrict__ ff1w0, const float* __restrict__ ff2w0,
    const float* __restrict__ taw0, const float* __restrict__ tbw0,
    const float* __restrict__ ff1w1, const float* __restrict__ ff2w1,
    const float* __restrict__ taw1, const float* __restrict__ tbw1,
    const float* __restrict__ ff1b1, const float* __restrict__ ff2b1,
    const float* __restrict__ tab1, const float* __restrict__ tbb1,
    const float* __restrict__ ff1w2, const float* __restrict__ ff2w2,
    const float* __restrict__ taw2, const float* __restrict__ tbw2,
    const float* __restrict__ ff1b2, const float* __restrict__ ff2b2,
    const float* __restrict__ tab2, const float* __restrict__ tbb2,
    const float* __restrict__ mask1, const float* __restrict__ mask2,
    float* __restrict__ out)
{
    const int L = threadIdx.x;
    const int b = blockIdx.x;

    // transposed LDS copies of the low-duty weight rows
    __shared__ float wCt[33 * 4];    // wCt[k*4+j] = lstm_wh[(128+j)*33+k]
    __shared__ float w0Bt[18 * 8];   // w0Bt[k*8+j] = tbw0[(10+j)*274+256+k]

    if (L < 33) {
        for (int j = 0; j < 4; j++) wCt[L * 4 + j] = lstm_wh[(128 + j) * 33 + L];
    }
    if (L < 18) {
        for (int j = 0; j < 8; j++) w0Bt[L * 8 + j] = tbw0[(10 + j) * 274 + 256 + L];
    }
    __syncthreads();

    const int jC = L & 3;            // wCt lane column
    const int j0B = (L - 4) & 7;     // w0Bt lane column (valid lanes 4..11)

    // ---- G weights: rows L, 64+L of stacked [132][33] lstm_wh ----
    float wA[33], wB[33];
#pragma unroll
    for (int k = 0; k < 33; k++) {
        wA[k] = lstm_wh[L * 33 + k];
        wB[k] = lstm_wh[(64 + L) * 33 + k];
    }
    // ---- L0 weights (h-part cols 256..273) ----
    float w0A[18];
    {
        const int m = L / 18, i = L - m * 18;
        const float* p0 = (m == 0) ? ff1w0 : (m == 1) ? ff2w0 : (m == 2) ? taw0 : tbw0;
#pragma unroll
        for (int k = 0; k < 18; k++) w0A[k] = p0[i * 274 + 256 + k];
    }
    // ---- L1 weights (full rows, len 30; ff rows masked) ----
    float w1[30], bias1;
    {
        const int d = (L < 48) ? L : 47;
        const int m = d / 12, i = d - m * 12;
        const float* p1 = (m == 0) ? ff1w1 : (m == 1) ? ff2w1 : (m == 2) ? taw1 : tbw1;
        const float* pb = (m == 0) ? ff1b1 : (m == 1) ? ff2b1 : (m == 2) ? tab1 : tbb1;
#pragma unroll
        for (int k = 0; k < 30; k++) {
            float mv = (m < 2) ? mask1[i * 30 + k] : 1.f;
            w1[k] = p1[i * 30 + k] * mv;
        }
        bias1 = (L < 48) ? pb[i] : 0.f;
    }
    // ---- L2 weights (full rows, len 15) ----
    float w2[15], bias2;
    {
        const int d = (L < 12) ? L : 11;
        const int m = d / 3, i = d - m * 3;
        const float* p2 = (m == 0) ? ff1w2 : (m == 1) ? ff2w2 : (m == 2) ? taw2 : tbw2;
        const float* pb = (m == 0) ? ff1b2 : (m == 1) ? ff2b2 : (m == 2) ? tab2 : tbb2;
#pragma unroll
        for (int k = 0; k < 15; k++) {
            float mv = (m < 2) ? mask2[i * 15 + k] : 1.f;
            w2[k] = p2[i * 15 + k] * mv;
        }
        bias2 = (L < 12) ? pb[i] : 0.f;
    }

    // ---- per-lane activation constants ----
    const float sA  = (L < 33) ? -T2E : -L2E;
    const float aA  = (L < 33) ? 2.f : 1.f;
    const float bA  = (L < 33) ? -1.f : 0.f;
    const float scB = (L >= 2 && L <= 34) ? -L2E : 0.f;
    const float s0  = (L < 36) ? -T2E : -L2E;
    const float a0c = (L < 36) ? 2.f : 1.f;
    const float b0c = (L < 36) ? -1.f : 0.f;
    const float s1  = (L < 24) ? -T2E : -L2E;
    const float a1c = (L < 24) ? 2.f : 1.f;
    const float b1c = (L < 24) ? -1.f : 0.f;
    const float s2  = (L < 6) ? -T2E : -L2E;
    const float a2c = (L < 6) ? 2.f : 1.f;
    const float b2c = (L < 6) ? -1.f : 0.f;

    // ---- per-lane bpermute byte indices ----
    const int xIgA = (4 * (33 + L)) & 255;
    const int xIgB = (4 * (L - 31)) & 255;
    const int xFg  = (4 * (2 + L)) & 255;
    const int xOgA = (4 * (35 + L)) & 255;
    const int xOgC = (4 * (L - 29)) & 255;
    const int x0s  = (4 * (L + 18)) & 255;
    const int x0tb = (4 * (L - 42)) & 255;
    const int x0ti = (4 * (L + 36)) & 255;
    const int x1s  = (4 * (L + 12)) & 255;
    const int x1ti = (4 * (L + 24)) & 255;
    const int x2s  = (4 * (L + 3)) & 255;
    const int x2ti = (4 * (L + 6)) & 255;

    // ---- state ----
    float hs[33];
#pragma unroll
    for (int k = 0; k < 33; k++) hs[k] = 0.f;
    float cc = 0.f;

    const float* Pb = P + (size_t)b * TSTEPS * NPAD;
    // 2-deep prefetch pipeline: cur (step t), nxt (step t+1)
    float c1 = Pb[L], c2 = Pb[64 + L], c3 = Pb[128 + L], c4 = Pb[192 + L];
    const float* P1 = Pb + NPAD;
    float n1 = P1[L], n2 = P1[64 + L], n3 = P1[128 + L], n4 = P1[192 + L];
    float* outp = out + (size_t)b * TSTEPS * 3 + L;

#pragma unroll 1
    for (int t = 0; t < TSTEPS; t++) {
        // issue loads for step t+2 (covers ~2 steps of latency)
        const int tf = (t + 2 < TSTEPS) ? t + 2 : TSTEPS - 1;
        const float* Pf = Pb + (size_t)tf * NPAD;
        const float f1 = Pf[L], f2_ = Pf[64 + L], f3 = Pf[128 + L], f4 = Pf[192 + L];

        // ---- Phase G: 132 gate dots in 3 shared loops (wC from LDS) ----
        float accA = c1, accB = c2, accC = c4;
#pragma unroll
        for (int k = 0; k < 33; k++) {
            accA = fmaf(wA[k], hs[k], accA);
            accB = fmaf(wB[k], hs[k], accB);
            accC = fmaf(wCt[k * 4 + jC], hs[k], accC);
        }
        const float actA = actf(accA, sA, 0.f, aA, bA);
        const float actB = actf(accB, -L2E, scB, 1.f, 0.f);
        const float actC = actf(accC, -L2E, 0.f, 1.f, 0.f);
        const float gIgA = bperm(xIgA, actA);
        const float gIgB = bperm(xIgB, actB);
        const float gFg  = bperm(xFg, actB);
        const float gOgA = bperm(xOgA, actB);
        const float gOgC = bperm(xOgC, actC);
        const float IG = (L < 31) ? gIgA : gIgB;
        const float OG = (L < 29) ? gOgA : gOgC;
        cc = fmaf(cc, gFg, actA * IG);
        const float hv = actf(cc, -T2E, 0.f, 2.f, -1.f) * OG;

        float hb[33];
#pragma unroll
        for (int k = 0; k < 33; k++) hb[k] = rl(hv, k);

        // ---- Phase L0: 72 dots (len 18), w0B from LDS ----
        float l0a = c3, l0b = c4;
#pragma unroll
        for (int k = 0; k < 18; k++) {
            l0a = fmaf(w0A[k], hb[k], l0a);
            l0b = fmaf(w0Bt[k * 8 + j0B], hb[k], l0b);
        }
        {
            const float tA = bperm(x0s, l0a);
            const float tB = bperm(x0tb, l0b);
            const float tb = (L < 46) ? tA : tB;
            const float xin = (L >= 36 && L < 54) ? l0a + tb : l0a;
            const float av = actf(xin, s0, 0.f, a0c, b0c);
            const float f2g = bperm(x0s, av);
            const float ti = bperm(x0ti, av);
            const float h0 = fmaf(ti, f2g - av, av);
#pragma unroll
            for (int k = 0; k < 18; k++) hs[k] = rl(h0, k);
        }

        // ---- Phase L1: 48 dots (len 30), xc1 = [hs[0..17], hb[18..29]] ----
        float l1 = bias1;
#pragma unroll
        for (int k = 0; k < 30; k++) l1 = fmaf(w1[k], (k < 18) ? hs[k] : hb[k], l1);
        {
            const float tb = bperm(x1s, l1);
            const float xin = (L >= 24 && L < 36) ? l1 + tb : l1;
            const float av = actf(xin, s1, 0.f, a1c, b1c);
            const float f2g = bperm(x1s, av);
            const float ti = bperm(x1ti, av);
            const float h1 = fmaf(ti, f2g - av, av);
#pragma unroll
            for (int k = 0; k < 12; k++) hs[18 + k] = rl(h1, k);
        }

        // ---- Phase L2: 12 dots (len 15), xc2 = [hs[18..29], hb[30..32]] ----
        float l2 = bias2;
#pragma unroll
        for (int k = 0; k < 15; k++) l2 = fmaf(w2[k], (k < 12) ? hs[18 + k] : hb[18 + k], l2);
        {
            const float tb = bperm(x2s, l2);
            const float xin = (L >= 6 && L < 9) ? l2 + tb : l2;
            const float av = actf(xin, s2, 0.f, a2c, b2c);
            const float f2g = bperm(x2s, av);
            const float ti = bperm(x2ti, av);
            const float h2 = fmaf(ti, f2g - av, av);
            if (L < 3) outp[(size_t)t * 3] = h2;
            hs[30] = rl(h2, 0); hs[31] = rl(h2, 1); hs[32] = rl(h2, 2);
        }

        c1 = n1; c2 = n2; c3 = n3; c4 = n4;
        n1 = f1; n2 = f2_; n3 = f3; n4 = f4;
    }
}

// ---------------------------------------------------------------------------
extern "C" void kernel_launch(void* const* d_in, const int* in_sizes, int n_in,
                              void* d_out, int out_size, void* d_ws, size_t ws_size,
                              hipStream_t stream) {
    const float* x       = (const float*)d_in[0];
    const float* fc1_w   = (const float*)d_in[1];
    const float* fc1_b   = (const float*)d_in[2];
    const float* lstm_wi = (const float*)d_in[3];
    const float* lstm_bi = (const float*)d_in[4];
    const float* lstm_wh = (const float*)d_in[5];
    const float* ff1w0 = (const float*)d_in[6];
    const float* ff2w0 = (const float*)d_in[7];
    const float* taw0  = (const float*)d_in[8];
    const float* tbw0  = (const float*)d_in[9];
    const float* ff1b0 = (const float*)d_in[10];
    const float* ff2b0 = (const float*)d_in[11];
    const float* tab0  = (const float*)d_in[12];
    const float* tbb0  = (const float*)d_in[13];
    const float* ff1w1 = (const float*)d_in[14];
    const float* ff2w1 = (const float*)d_in[15];
    const float* taw1  = (const float*)d_in[16];
    const float* tbw1  = (const float*)d_in[17];
    const float* ff1b1 = (const float*)d_in[18];
    const float* ff2b1 = (const float*)d_in[19];
    const float* tab1  = (const float*)d_in[20];
    const float* tbb1  = (const float*)d_in[21];
    const float* ff1w2 = (const float*)d_in[22];
    const float* ff2w2 = (const float*)d_in[23];
    const float* taw2  = (const float*)d_in[24];
    const float* tbw2  = (const float*)d_in[25];
    const float* ff1b2 = (const float*)d_in[26];
    const float* ff2b2 = (const float*)d_in[27];
    const float* tab2  = (const float*)d_in[28];
    const float* tbb2  = (const float*)d_in[29];
    const float* mask0 = (const float*)d_in[30];
    const float* mask1 = (const float*)d_in[31];
    const float* mask2 = (const float*)d_in[32];

    float* Wc = (float*)d_ws;            // 512*256 floats
    float* bc = Wc + 512 * NW;           // 256 floats
    float* P  = bc + NW;                 // 32768*208 floats
    float* outp = (float*)d_out;

    fold_kernel<<<256, 256, 0, stream>>>(fc1_w, fc1_b, lstm_wi, lstm_bi,
                                         ff1w0, ff2w0, taw0, tbw0,
                                         ff1b0, ff2b0, tab0, tbb0, mask0, Wc, bc);
    gemm_kernel<<<dim3(BT / 64, 4), 256, 0, stream>>>(x, Wc, bc, P);
    scan_kernel<<<NBATCH, 64, 0, stream>>>(P, lstm_wh,
                                           ff1w0, ff2w0, taw0, tbw0,
                                           ff1w1, ff2w1, taw1, tbw1,
                                           ff1b1, ff2b1, tab1, tbb1,
                                           ff1w2, ff2w2, taw2, tbw2,
                                           ff1b2, ff2b2, tab2, tbb2,
                                           mask1, mask2, outp);
}

// Round 5
// 767.900 us; speedup vs baseline: 1.0019x; 1.0019x over previous
//
#include <hip/hip_runtime.h>
#include <hip/hip_bf16.h>

// Problem constants
#define BT 32768      // B*T = 64*512
#define TSTEPS 512
#define NBATCH 64
#define KDIM 512      // IN_DIM
#define NPAD 208      // P row stride
#define NW 256        // Wc padded cols

#define L2E 1.4426950408889634f
#define T2E 2.8853900817779268f

__device__ __forceinline__ float rl(float v, int lane) {
    return __int_as_float(__builtin_amdgcn_readlane(__float_as_int(v), lane));
}
__device__ __forceinline__ float bperm(int byteidx, float v) {
    return __int_as_float(__builtin_amdgcn_ds_bpermute(byteidx, __float_as_int(v)));
}
// unified activation: a * rcp(1 + exp2(s*x + sc)) + b
__device__ __forceinline__ float actf(float x, float s, float sc, float a, float b) {
    float e = exp2f(fmaf(s, x, sc));
    return fmaf(a, __builtin_amdgcn_rcpf(1.f + e), b);
}

// P column layout (dot-major):
//   cols 0..127   = z dots 0..127            (dot d = gate*33 + neuron)
//   cols 128..191 = layer0 dots 0..63        (dot e = m*18 + i)
//   cols 192..195 = z dots 128..131
//   cols 196..203 = layer0 dots 64..71
//   cols 204..207 = pad (zeros)
__device__ __forceinline__ int permpos(int o) {
    if (o < 128) return o;
    if (o < 132) return o + 64;
    if (o < 196) return o - 4;
    return o;
}

// ---------------------------------------------------------------------------
// Kernel 1: fold fc1 into the stacked scan-input projection (permuted cols).
// ---------------------------------------------------------------------------
__global__ __launch_bounds__(256) void fold_kernel(
    const float* __restrict__ fc1_w, const float* __restrict__ fc1_b,
    const float* __restrict__ lstm_wi, const float* __restrict__ lstm_bi,
    const float* __restrict__ ff1w0, const float* __restrict__ ff2w0,
    const float* __restrict__ taw0, const float* __restrict__ tbw0,
    const float* __restrict__ ff1b0, const float* __restrict__ ff2b0,
    const float* __restrict__ tab0, const float* __restrict__ tbb0,
    const float* __restrict__ mask0,
    float* __restrict__ Wc, float* __restrict__ bc)
{
    const int o = blockIdx.x;
    const int t = threadIdx.x;
    const int p = permpos(o);
    __shared__ float wrow[256];
    __shared__ float red[256];

    float wl = 0.f, b0 = 0.f;
    if (o < 132)      { wl = lstm_wi[o * 256 + t];                         b0 = lstm_bi[o]; }
    else if (o < 150) { int i = o - 132; wl = ff1w0[i * 274 + t] * mask0[i * 274 + t]; b0 = ff1b0[i]; }
    else if (o < 168) { int i = o - 150; wl = ff2w0[i * 274 + t] * mask0[i * 274 + t]; b0 = ff2b0[i]; }
    else if (o < 186) { int i = o - 168; wl = taw0[i * 274 + t];           b0 = tab0[i]; }
    else if (o < 204) { int i = o - 186; wl = tbw0[i * 274 + t];           b0 = tbb0[i]; }
    wrow[t] = wl;
    __syncthreads();

    float acc0 = 0.f, acc1 = 0.f;
    for (int l = 0; l < 256; l++) {
        float w = wrow[l];
        acc0 = fmaf(fc1_w[l * 512 + t], w, acc0);
        acc1 = fmaf(fc1_w[l * 512 + t + 256], w, acc1);
    }
    Wc[(size_t)t * NW + p] = acc0;
    Wc[(size_t)(t + 256) * NW + p] = acc1;

    red[t] = fc1_b[t] * wl;
    __syncthreads();
    for (int s = 128; s > 0; s >>= 1) {
        if (t < s) red[t] += red[t + s];
        __syncthreads();
    }
    if (t == 0) bc[p] = red[0] + b0;
}

// ---------------------------------------------------------------------------
// Kernel 2: P[m][n] = sum_k X[m][k]*Wc[k][n] + bc[n], fp32 LDS-tiled GEMM.
// ---------------------------------------------------------------------------
__global__ __launch_bounds__(256) void gemm_kernel(
    const float* __restrict__ X, const float* __restrict__ Wc,
    const float* __restrict__ bc, float* __restrict__ P)
{
    __shared__ float As[16][68];
    __shared__ float Bs[16][64];
    const int tid = threadIdx.x;
    const int m0 = blockIdx.x * 64;
    const int n0 = blockIdx.y * 64;
    const int lr = tid >> 2;
    const int lc = (tid & 3) << 2;
    const int wr = tid >> 4;
    const int wc = (tid & 15) << 2;
    const int tm = (tid >> 4) << 2;
    const int tn = (tid & 15) << 2;

    float acc[4][4];
#pragma unroll
    for (int i = 0; i < 4; i++)
#pragma unroll
        for (int j = 0; j < 4; j++) acc[i][j] = 0.f;

    for (int k0 = 0; k0 < KDIM; k0 += 16) {
        float4 av = *(const float4*)(X + (size_t)(m0 + lr) * KDIM + k0 + lc);
        float4 bv = *(const float4*)(Wc + (size_t)(k0 + wr) * NW + n0 + wc);
        __syncthreads();
        As[lc + 0][lr] = av.x; As[lc + 1][lr] = av.y;
        As[lc + 2][lr] = av.z; As[lc + 3][lr] = av.w;
        *(float4*)&Bs[wr][wc] = bv;
        __syncthreads();
#pragma unroll
        for (int k = 0; k < 16; k++) {
            float4 a = *(const float4*)&As[k][tm];
            float4 b = *(const float4*)&Bs[k][tn];
            acc[0][0] = fmaf(a.x, b.x, acc[0][0]); acc[0][1] = fmaf(a.x, b.y, acc[0][1]);
            acc[0][2] = fmaf(a.x, b.z, acc[0][2]); acc[0][3] = fmaf(a.x, b.w, acc[0][3]);
            acc[1][0] = fmaf(a.y, b.x, acc[1][0]); acc[1][1] = fmaf(a.y, b.y, acc[1][1]);
            acc[1][2] = fmaf(a.y, b.z, acc[1][2]); acc[1][3] = fmaf(a.y, b.w, acc[1][3]);
            acc[2][0] = fmaf(a.z, b.x, acc[2][0]); acc[2][1] = fmaf(a.z, b.y, acc[2][1]);
            acc[2][2] = fmaf(a.z, b.z, acc[2][2]); acc[2][3] = fmaf(a.z, b.w, acc[2][3]);
            acc[3][0] = fmaf(a.w, b.x, acc[3][0]); acc[3][1] = fmaf(a.w, b.y, acc[3][1]);
            acc[3][2] = fmaf(a.w, b.z, acc[3][2]); acc[3][3] = fmaf(a.w, b.w, acc[3][3]);
        }
    }

    if (n0 + tn < NPAD) {
        float4 bias = *(const float4*)(bc + n0 + tn);
#pragma unroll
        for (int i = 0; i < 4; i++) {
            float4 r;
            r.x = acc[i][0] + bias.x; r.y = acc[i][1] + bias.y;
            r.z = acc[i][2] + bias.z; r.w = acc[i][3] + bias.w;
            *(float4*)(P + (size_t)(m0 + tm + i) * NPAD + n0 + tn) = r;
        }
    }
}

// ---------------------------------------------------------------------------
// Kernel 3: persistent scan, one wave per batch element.
// amdgpu_waves_per_eu(1,1): we launch 64 single-wave blocks on 256 CUs, so
// occupancy >1 wave/EU is worthless — give the wave the whole 512-VGPR file
// so the ~220-float working set (weights + state + prefetch) stays resident.
// Single h[33] state array: G reads old h, overwrites with LSTM h via
// readlane; L0/L1/L2 overwrite segments [0,18)/[18,30)/[30,33) after last use.
// ---------------------------------------------------------------------------
__global__ __launch_bounds__(64)
__attribute__((amdgpu_waves_per_eu(1, 1)))
void scan_kernel(
    const float* __restrict__ P, const float* __restrict__ lstm_wh,
    const float* __restrict__ ff1w0, const float* __restrict__ ff2w0,
    const float* __restrict__ taw0, const float* __restrict__ tbw0,
    const float* __restrict__ ff1w1, const float* __restrict__ ff2w1,
    const float* __restrict__ taw1, const float* __restrict__ tbw1,
    const float* __restrict__ ff1b1, const float* __restrict__ ff2b1,
    const float* __restrict__ tab1, const float* __restrict__ tbb1,
    const float* __restrict__ ff1w2, const float* __restrict__ ff2w2,
    const float* __restrict__ taw2, const float* __restrict__ tbw2,
    const float* __restrict__ ff1b2, const float* __restrict__ ff2b2,
    const float* __restrict__ tab2, const float* __restrict__ tbb2,
    const float* __restrict__ mask1, const float* __restrict__ mask2,
    float* __restrict__ out)
{
    const int L = threadIdx.x;
    const int b = blockIdx.x;

    // transposed LDS copies of the low-duty weight rows
    __shared__ float wCt[33 * 4];    // wCt[k*4+j] = lstm_wh[(128+j)*33+k]
    __shared__ float w0Bt[18 * 8];   // w0Bt[k*8+j] = tbw0[(10+j)*274+256+k]

    if (L < 33) {
        for (int j = 0; j < 4; j++) wCt[L * 4 + j] = lstm_wh[(128 + j) * 33 + L];
    }
    if (L < 18) {
        for (int j = 0; j < 8; j++) w0Bt[L * 8 + j] = tbw0[(10 + j) * 274 + 256 + L];
    }
    __syncthreads();

    const int jC = L & 3;            // wCt lane column
    const int j0B = (L - 4) & 7;     // w0Bt lane column (valid lanes 4..11)

    // ---- G weights: rows L, 64+L of stacked [132][33] lstm_wh ----
    float wA[33], wB[33];
#pragma unroll
    for (int k = 0; k < 33; k++) {
        wA[k] = lstm_wh[L * 33 + k];
        wB[k] = lstm_wh[(64 + L) * 33 + k];
    }
    // ---- L0 weights (h-part cols 256..273) ----
    float w0A[18];
    {
        const int m = L / 18, i = L - m * 18;
        const float* p0 = (m == 0) ? ff1w0 : (m == 1) ? ff2w0 : (m == 2) ? taw0 : tbw0;
#pragma unroll
        for (int k = 0; k < 18; k++) w0A[k] = p0[i * 274 + 256 + k];
    }
    // ---- L1 weights (full rows, len 30; ff rows masked) ----
    float w1[30], bias1;
    {
        const int d = (L < 48) ? L : 47;
        const int m = d / 12, i = d - m * 12;
        const float* p1 = (m == 0) ? ff1w1 : (m == 1) ? ff2w1 : (m == 2) ? taw1 : tbw1;
        const float* pb = (m == 0) ? ff1b1 : (m == 1) ? ff2b1 : (m == 2) ? tab1 : tbb1;
#pragma unroll
        for (int k = 0; k < 30; k++) {
            float mv = (m < 2) ? mask1[i * 30 + k] : 1.f;
            w1[k] = p1[i * 30 + k] * mv;
        }
        bias1 = (L < 48) ? pb[i] : 0.f;
    }
    // ---- L2 weights (full rows, len 15) ----
    float w2[15], bias2;
    {
        const int d = (L < 12) ? L : 11;
        const int m = d / 3, i = d - m * 3;
        const float* p2 = (m == 0) ? ff1w2 : (m == 1) ? ff2w2 : (m == 2) ? taw2 : tbw2;
        const float* pb = (m == 0) ? ff1b2 : (m == 1) ? ff2b2 : (m == 2) ? tab2 : tbb2;
#pragma unroll
        for (int k = 0; k < 15; k++) {
            float mv = (m < 2) ? mask2[i * 15 + k] : 1.f;
            w2[k] = p2[i * 15 + k] * mv;
        }
        bias2 = (L < 12) ? pb[i] : 0.f;
    }

    // ---- per-lane activation constants ----
    const float sA  = (L < 33) ? -T2E : -L2E;
    const float aA  = (L < 33) ? 2.f : 1.f;
    const float bA  = (L < 33) ? -1.f : 0.f;
    const float scB = (L >= 2 && L <= 34) ? -L2E : 0.f;
    const float s0  = (L < 36) ? -T2E : -L2E;
    const float a0c = (L < 36) ? 2.f : 1.f;
    const float b0c = (L < 36) ? -1.f : 0.f;
    const float s1  = (L < 24) ? -T2E : -L2E;
    const float a1c = (L < 24) ? 2.f : 1.f;
    const float b1c = (L < 24) ? -1.f : 0.f;
    const float s2  = (L < 6) ? -T2E : -L2E;
    const float a2c = (L < 6) ? 2.f : 1.f;
    const float b2c = (L < 6) ? -1.f : 0.f;

    // ---- per-lane bpermute byte indices ----
    const int xIgA = (4 * (33 + L)) & 255;
    const int xIgB = (4 * (L - 31)) & 255;
    const int xFg  = (4 * (2 + L)) & 255;
    const int xOgA = (4 * (35 + L)) & 255;
    const int xOgC = (4 * (L - 29)) & 255;
    const int x0s  = (4 * (L + 18)) & 255;
    const int x0tb = (4 * (L - 42)) & 255;
    const int x0ti = (4 * (L + 36)) & 255;
    const int x1s  = (4 * (L + 12)) & 255;
    const int x1ti = (4 * (L + 24)) & 255;
    const int x2s  = (4 * (L + 3)) & 255;
    const int x2ti = (4 * (L + 6)) & 255;

    // ---- state: single merged array (old CfC state / LSTM h / new CfC state) ----
    float h[33];
#pragma unroll
    for (int k = 0; k < 33; k++) h[k] = 0.f;
    float cc = 0.f;

    const float* Pb = P + (size_t)b * TSTEPS * NPAD;
    // 2-deep prefetch pipeline
    float c1 = Pb[L], c2 = Pb[64 + L], c3 = Pb[128 + L], c4 = Pb[192 + L];
    const float* P1 = Pb + NPAD;
    float n1 = P1[L], n2 = P1[64 + L], n3 = P1[128 + L], n4 = P1[192 + L];
    float* outp = out + (size_t)b * TSTEPS * 3 + L;

#pragma unroll 1
    for (int t = 0; t < TSTEPS; t++) {
        // issue loads for step t+2
        const int tf = (t + 2 < TSTEPS) ? t + 2 : TSTEPS - 1;
        const float* Pf = Pb + (size_t)tf * NPAD;
        const float f1 = Pf[L], f2_ = Pf[64 + L], f3 = Pf[128 + L], f4 = Pf[192 + L];

        // ---- Phase G: 132 gate dots in 3 shared loops (wC from LDS) ----
        float accA = c1, accB = c2, accC = c4;
#pragma unroll
        for (int k = 0; k < 33; k++) {
            accA = fmaf(wA[k], h[k], accA);
            accB = fmaf(wB[k], h[k], accB);
            accC = fmaf(wCt[k * 4 + jC], h[k], accC);
        }
        const float actA = actf(accA, sA, 0.f, aA, bA);
        const float actB = actf(accB, -L2E, scB, 1.f, 0.f);
        const float actC = actf(accC, -L2E, 0.f, 1.f, 0.f);
        const float gIgA = bperm(xIgA, actA);
        const float gIgB = bperm(xIgB, actB);
        const float gFg  = bperm(xFg, actB);
        const float gOgA = bperm(xOgA, actB);
        const float gOgC = bperm(xOgC, actC);
        const float IG = (L < 31) ? gIgA : gIgB;
        const float OG = (L < 29) ? gOgA : gOgC;
        cc = fmaf(cc, gFg, actA * IG);
        const float hv = actf(cc, -T2E, 0.f, 2.f, -1.f) * OG;

        // broadcast LSTM h into the merged state array
#pragma unroll
        for (int k = 0; k < 33; k++) h[k] = rl(hv, k);

        // ---- Phase L0: 72 dots (len 18), w0B from LDS ----
        float l0a = c3, l0b = c4;
#pragma unroll
        for (int k = 0; k < 18; k++) {
            l0a = fmaf(w0A[k], h[k], l0a);
            l0b = fmaf(w0Bt[k * 8 + j0B], h[k], l0b);
        }
        {
            const float tA = bperm(x0s, l0a);
            const float tB = bperm(x0tb, l0b);
            const float tb = (L < 46) ? tA : tB;
            const float xin = (L >= 36 && L < 54) ? l0a + tb : l0a;
            const float av = actf(xin, s0, 0.f, a0c, b0c);
            const float f2g = bperm(x0s, av);
            const float ti = bperm(x0ti, av);
            const float h0 = fmaf(ti, f2g - av, av);
#pragma unroll
            for (int k = 0; k < 18; k++) h[k] = rl(h0, k);
        }

        // ---- Phase L1: 48 dots (len 30), xc1 = h[0..29] ----
        float l1 = bias1;
#pragma unroll
        for (int k = 0; k < 30; k++) l1 = fmaf(w1[k], h[k], l1);
        {
            const float tb = bperm(x1s, l1);
            const float xin = (L >= 24 && L < 36) ? l1 + tb : l1;
            const float av = actf(xin, s1, 0.f, a1c, b1c);
            const float f2g = bperm(x1s, av);
            const float ti = bperm(x1ti, av);
            const float h1 = fmaf(ti, f2g - av, av);
#pragma unroll
            for (int k = 0; k < 12; k++) h[18 + k] = rl(h1, k);
        }

        // ---- Phase L2: 12 dots (len 15), xc2 = h[18..32] ----
        float l2 = bias2;
#pragma unroll
        for (int k = 0; k < 15; k++) l2 = fmaf(w2[k], h[18 + k], l2);
        {
            const float tb = bperm(x2s, l2);
            const float xin = (L >= 6 && L < 9) ? l2 + tb : l2;
            const float av = actf(xin, s2, 0.f, a2c, b2c);
            const float f2g = bperm(x2s, av);
            const float ti = bperm(x2ti, av);
            const float h2 = fmaf(ti, f2g - av, av);
            if (L < 3) outp[(size_t)t * 3] = h2;
            h[30] = rl(h2, 0); h[31] = rl(h2, 1); h[32] = rl(h2, 2);
        }

        c1 = n1; c2 = n2; c3 = n3; c4 = n4;
        n1 = f1; n2 = f2_; n3 = f3; n4 = f4;
    }
}

// ---------------------------------------------------------------------------
extern "C" void kernel_launch(void* const* d_in, const int* in_sizes, int n_in,
                              void* d_out, int out_size, void* d_ws, size_t ws_size,
                              hipStream_t stream) {
    const float* x       = (const float*)d_in[0];
    const float* fc1_w   = (const float*)d_in[1];
    const float* fc1_b   = (const float*)d_in[2];
    const float* lstm_wi = (const float*)d_in[3];
    const float* lstm_bi = (const float*)d_in[4];
    const float* lstm_wh = (const float*)d_in[5];
    const float* ff1w0 = (const float*)d_in[6];
    const float* ff2w0 = (const float*)d_in[7];
    const float* taw0  = (const float*)d_in[8];
    const float* tbw0  = (const float*)d_in[9];
    const float* ff1b0 = (const float*)d_in[10];
    const float* ff2b0 = (const float*)d_in[11];
    const float* tab0  = (const float*)d_in[12];
    const float* tbb0  = (const float*)d_in[13];
    const float* ff1w1 = (const float*)d_in[14];
    const float* ff2w1 = (const float*)d_in[15];
    const float* taw1  = (const float*)d_in[16];
    const float* tbw1  = (const float*)d_in[17];
    const float* ff1b1 = (const float*)d_in[18];
    const float* ff2b1 = (const float*)d_in[19];
    const float* tab1  = (const float*)d_in[20];
    const float* tbb1  = (const float*)d_in[21];
    const float* ff1w2 = (const float*)d_in[22];
    const float* ff2w2 = (const float*)d_in[23];
    const float* taw2  = (const float*)d_in[24];
    const float* tbw2  = (const float*)d_in[25];
    const float* ff1b2 = (const float*)d_in[26];
    const float* ff2b2 = (const float*)d_in[27];
    const float* tab2  = (const float*)d_in[28];
    const float* tbb2  = (const float*)d_in[29];
    const float* mask0 = (const float*)d_in[30];
    const float* mask1 = (const float*)d_in[31];
    const float* mask2 = (const float*)d_in[32];

    float* Wc = (float*)d_ws;            // 512*256 floats
    float* bc = Wc + 512 * NW;           // 256 floats
    float* P  = bc + NW;                 // 32768*208 floats
    float* outp = (float*)d_out;

    fold_kernel<<<256, 256, 0, stream>>>(fc1_w, fc1_b, lstm_wi, lstm_bi,
                                         ff1w0, ff2w0, taw0, tbw0,
                                         ff1b0, ff2b0, tab0, tbb0, mask0, Wc, bc);
    gemm_kernel<<<dim3(BT / 64, 4), 256, 0, stream>>>(x, Wc, bc, P);
    scan_kernel<<<NBATCH, 64, 0, stream>>>(P, lstm_wh,
                                           ff1w0, ff2w0, taw0, tbw0,
                                           ff1w1, ff2w1, taw1, tbw1,
                                           ff1b1, ff2b1, tab1, tbb1,
                                           ff1w2, ff2w2, taw2, tbw2,
                                           ff1b2, ff2b2, tab2, tbb2,
                                           mask1, mask2, outp);
}

// Round 6
// 685.309 us; speedup vs baseline: 1.1227x; 1.1205x over previous
//
#include <hip/hip_runtime.h>
#include <hip/hip_bf16.h>

// Problem constants
#define BT 32768      // B*T = 64*512
#define TSTEPS 512
#define NBATCH 64
#define KDIM 512      // IN_DIM
#define NPAD 192      // P row stride == logical cols (132 z + 54 l0 + 6 pad)
#define NW 192        // Wc cols

#define L2E 1.4426950408889634f
#define T2E 2.8853900817779268f

__device__ __forceinline__ float rl(float v, int lane) {
    return __int_as_float(__builtin_amdgcn_readlane(__float_as_int(v), lane));
}
__device__ __forceinline__ float bperm(int byteidx, float v) {
    return __int_as_float(__builtin_amdgcn_ds_bpermute(byteidx, __float_as_int(v)));
}
// unified activation: a * rcp(1 + exp2(s*x + sc)) + b
__device__ __forceinline__ float actf(float x, float s, float sc, float a, float b) {
    float e = exp2f(fmaf(s, x, sc));
    return fmaf(a, __builtin_amdgcn_rcpf(1.f + e), b);
}

// ---------------------------------------------------------------------------
// Kernel 1: fold fc1 into the stacked scan-input projection.
// Column o (identity layout):
//   o in [0,132):   z dot o (gate g=o/33, neuron i=o%33): lstm_wi row o
//   o in [132,186): L0 dot e=o-132, e=m*18+i, m in {ff1,ff2,ta+tb merged}
//   o in [186,192): zero pad
// ---------------------------------------------------------------------------
__global__ __launch_bounds__(256) void fold_kernel(
    const float* __restrict__ fc1_w, const float* __restrict__ fc1_b,
    const float* __restrict__ lstm_wi, const float* __restrict__ lstm_bi,
    const float* __restrict__ ff1w0, const float* __restrict__ ff2w0,
    const float* __restrict__ taw0, const float* __restrict__ tbw0,
    const float* __restrict__ ff1b0, const float* __restrict__ ff2b0,
    const float* __restrict__ tab0, const float* __restrict__ tbb0,
    const float* __restrict__ mask0,
    float* __restrict__ Wc, float* __restrict__ bc)
{
    const int o = blockIdx.x;   // 0..191
    const int t = threadIdx.x;  // 0..255 = latent index l
    __shared__ float wrow[256];
    __shared__ float red[256];

    float wl = 0.f, b0 = 0.f;
    if (o < 132) { wl = lstm_wi[o * 256 + t]; b0 = lstm_bi[o]; }
    else if (o < 186) {
        const int e = o - 132, m = e / 18, i = e - m * 18;
        if (m == 0)      { wl = ff1w0[i * 274 + t] * mask0[i * 274 + t]; b0 = ff1b0[i]; }
        else if (m == 1) { wl = ff2w0[i * 274 + t] * mask0[i * 274 + t]; b0 = ff2b0[i]; }
        else             { wl = taw0[i * 274 + t] + tbw0[i * 274 + t];   b0 = tab0[i] + tbb0[i]; }
    }
    wrow[t] = wl;
    __syncthreads();

    float acc0 = 0.f, acc1 = 0.f;
    for (int l = 0; l < 256; l++) {
        float w = wrow[l];
        acc0 = fmaf(fc1_w[l * 512 + t], w, acc0);
        acc1 = fmaf(fc1_w[l * 512 + t + 256], w, acc1);
    }
    Wc[(size_t)t * NW + o] = acc0;
    Wc[(size_t)(t + 256) * NW + o] = acc1;

    red[t] = fc1_b[t] * wl;
    __syncthreads();
    for (int s = 128; s > 0; s >>= 1) {
        if (t < s) red[t] += red[t + s];
        __syncthreads();
    }
    if (t == 0) bc[o] = red[0] + b0;
}

// ---------------------------------------------------------------------------
// Kernel 2: P[m][n] = sum_k X[m][k]*Wc[k][n] + bc[n], fp32 LDS-tiled GEMM.
// M=32768, K=512, N=192. Tile 64x64x16, grid (512, 3).
// ---------------------------------------------------------------------------
__global__ __launch_bounds__(256) void gemm_kernel(
    const float* __restrict__ X, const float* __restrict__ Wc,
    const float* __restrict__ bc, float* __restrict__ P)
{
    __shared__ float As[16][68];
    __shared__ float Bs[16][64];
    const int tid = threadIdx.x;
    const int m0 = blockIdx.x * 64;
    const int n0 = blockIdx.y * 64;
    const int lr = tid >> 2;
    const int lc = (tid & 3) << 2;
    const int wr = tid >> 4;
    const int wc = (tid & 15) << 2;
    const int tm = (tid >> 4) << 2;
    const int tn = (tid & 15) << 2;

    float acc[4][4];
#pragma unroll
    for (int i = 0; i < 4; i++)
#pragma unroll
        for (int j = 0; j < 4; j++) acc[i][j] = 0.f;

    for (int k0 = 0; k0 < KDIM; k0 += 16) {
        float4 av = *(const float4*)(X + (size_t)(m0 + lr) * KDIM + k0 + lc);
        float4 bv = *(const float4*)(Wc + (size_t)(k0 + wr) * NW + n0 + wc);
        __syncthreads();
        As[lc + 0][lr] = av.x; As[lc + 1][lr] = av.y;
        As[lc + 2][lr] = av.z; As[lc + 3][lr] = av.w;
        *(float4*)&Bs[wr][wc] = bv;
        __syncthreads();
#pragma unroll
        for (int k = 0; k < 16; k++) {
            float4 a = *(const float4*)&As[k][tm];
            float4 b = *(const float4*)&Bs[k][tn];
            acc[0][0] = fmaf(a.x, b.x, acc[0][0]); acc[0][1] = fmaf(a.x, b.y, acc[0][1]);
            acc[0][2] = fmaf(a.x, b.z, acc[0][2]); acc[0][3] = fmaf(a.x, b.w, acc[0][3]);
            acc[1][0] = fmaf(a.y, b.x, acc[1][0]); acc[1][1] = fmaf(a.y, b.y, acc[1][1]);
            acc[1][2] = fmaf(a.y, b.z, acc[1][2]); acc[1][3] = fmaf(a.y, b.w, acc[1][3]);
            acc[2][0] = fmaf(a.z, b.x, acc[2][0]); acc[2][1] = fmaf(a.z, b.y, acc[2][1]);
            acc[2][2] = fmaf(a.z, b.z, acc[2][2]); acc[2][3] = fmaf(a.z, b.w, acc[2][3]);
            acc[3][0] = fmaf(a.w, b.x, acc[3][0]); acc[3][1] = fmaf(a.w, b.y, acc[3][1]);
            acc[3][2] = fmaf(a.w, b.z, acc[3][2]); acc[3][3] = fmaf(a.w, b.w, acc[3][3]);
        }
    }

    {
        float4 bias = *(const float4*)(bc + n0 + tn);
#pragma unroll
        for (int i = 0; i < 4; i++) {
            float4 r;
            r.x = acc[i][0] + bias.x; r.y = acc[i][1] + bias.y;
            r.z = acc[i][2] + bias.z; r.w = acc[i][3] + bias.w;
            *(float4*)(P + (size_t)(m0 + tm + i) * NPAD + n0 + tn) = r;
        }
    }
}

// ---------------------------------------------------------------------------
// Kernel 3: persistent scan, one wave per batch element.
// ta/tb merged into one dot per CfC neuron (sig(ta+tb)=sig(xc@(aw+bw)+ab+bb)):
//   G:  z dots 0..63 (accA, c1), 64..127 (accB, c2), 128..131 (accC, c3
//       lanes 0..3, weights via LDS wCt).
//   L0: 54 dots (m*18+i, m in {ff1,ff2,tsum}) on lanes 4..57, P-precomp = c3.
//   L1: 36 dots lanes 0..35.  L2: 9 dots lanes 0..8.
// One bperm gather stage per phase; even/odd split accumulator chains.
// ---------------------------------------------------------------------------
__global__ __launch_bounds__(64)
__attribute__((amdgpu_waves_per_eu(1, 1)))
void scan_kernel(
    const float* __restrict__ P, const float* __restrict__ lstm_wh,
    const float* __restrict__ ff1w0, const float* __restrict__ ff2w0,
    const float* __restrict__ taw0, const float* __restrict__ tbw0,
    const float* __restrict__ ff1w1, const float* __restrict__ ff2w1,
    const float* __restrict__ taw1, const float* __restrict__ tbw1,
    const float* __restrict__ ff1b1, const float* __restrict__ ff2b1,
    const float* __restrict__ tab1, const float* __restrict__ tbb1,
    const float* __restrict__ ff1w2, const float* __restrict__ ff2w2,
    const float* __restrict__ taw2, const float* __restrict__ tbw2,
    const float* __restrict__ ff1b2, const float* __restrict__ ff2b2,
    const float* __restrict__ tab2, const float* __restrict__ tbb2,
    const float* __restrict__ mask1, const float* __restrict__ mask2,
    float* __restrict__ out)
{
    const int L = threadIdx.x;
    const int b = blockIdx.x;

    // LDS copy of the 4 straggler z rows (dots 128..131), transposed
    __shared__ float wCt[33 * 4];    // wCt[k*4+j] = lstm_wh[(128+j)*33+k]
    if (L < 33) {
        for (int j = 0; j < 4; j++) wCt[L * 4 + j] = lstm_wh[(128 + j) * 33 + L];
    }
    __syncthreads();
    const int jC = L & 3;

    // ---- G weights: rows L, 64+L of stacked [132][33] lstm_wh ----
    float wA[33], wB[33];
#pragma unroll
    for (int k = 0; k < 33; k++) {
        wA[k] = lstm_wh[L * 33 + k];
        wB[k] = lstm_wh[(64 + L) * 33 + k];
    }
    // ---- L0 weights: dot e=L-4 (clamped), m=e/18; ta+tb merged ----
    float w0[18];
    {
        int e = L - 4; e = (e < 0) ? 0 : ((e > 53) ? 53 : e);
        const int m = e / 18, i = e - m * 18;
        const float* pa = (m == 0) ? ff1w0 : (m == 1) ? ff2w0 : taw0;
#pragma unroll
        for (int k = 0; k < 18; k++) {
            float w = pa[i * 274 + 256 + k];
            if (m == 2) w += tbw0[i * 274 + 256 + k];
            w0[k] = w;
        }
    }
    // ---- L1 weights: dot d=m*12+i on lanes 0..35 ----
    float w1[30], bias1;
    {
        const int d = (L < 36) ? L : 35;
        const int m = d / 12, i = d - m * 12;
        const float* pa = (m == 0) ? ff1w1 : (m == 1) ? ff2w1 : taw1;
#pragma unroll
        for (int k = 0; k < 30; k++) {
            float w = pa[i * 30 + k];
            if (m == 2) w += tbw1[i * 30 + k];
            else w *= mask1[i * 30 + k];
            w1[k] = w;
        }
        bias1 = (m == 0) ? ff1b1[i] : (m == 1) ? ff2b1[i] : (tab1[i] + tbb1[i]);
    }
    // ---- L2 weights: dot d=m*3+i on lanes 0..8 ----
    float w2[15], bias2;
    {
        const int d = (L < 9) ? L : 8;
        const int m = d / 3, i = d - m * 3;
        const float* pa = (m == 0) ? ff1w2 : (m == 1) ? ff2w2 : taw2;
#pragma unroll
        for (int k = 0; k < 15; k++) {
            float w = pa[i * 15 + k];
            if (m == 2) w += tbw2[i * 15 + k];
            else w *= mask2[i * 15 + k];
            w2[k] = w;
        }
        bias2 = (m == 0) ? ff1b2[i] : (m == 1) ? ff2b2[i] : (tab2[i] + tbb2[i]);
    }

    // ---- per-lane activation constants ----
    const float sA  = (L < 33) ? -T2E : -L2E;           // accA: ia tanh, ig sig
    const float aA  = (L < 33) ? 2.f : 1.f;
    const float bA  = (L < 33) ? -1.f : 0.f;
    const float scB = (L >= 2 && L <= 34) ? -L2E : 0.f; // accB: fg gets sig(x+1)
    const float s0  = (L < 40) ? -T2E : -L2E;           // L0 act: lanes 4..39 tanh, 40..57 sig
    const float a0c = (L < 40) ? 2.f : 1.f;
    const float b0c = (L < 40) ? -1.f : 0.f;
    const float s1  = (L < 24) ? -T2E : -L2E;           // L1: 0..23 tanh, 24..35 sig
    const float a1c = (L < 24) ? 2.f : 1.f;
    const float b1c = (L < 24) ? -1.f : 0.f;
    const float s2  = (L < 6) ? -T2E : -L2E;            // L2: 0..5 tanh, 6..8 sig
    const float a2c = (L < 6) ? 2.f : 1.f;
    const float b2c = (L < 6) ? -1.f : 0.f;

    // ---- per-lane bpermute byte indices ----
    const int xIgA = (4 * (33 + L)) & 255;   // ig neuron L from accA lane 33+L (L<=30)
    const int xIgB = (4 * (L - 31)) & 255;   // ig neuron 31,32 from accB lanes 0,1
    const int xFg  = (4 * (2 + L)) & 255;    // fg neuron L from accB lane 2+L
    const int xOgA = (4 * (35 + L)) & 255;   // og neuron L from accB lane 35+L (L<=28)
    const int xOgC = (4 * (L - 29)) & 255;   // og neuron 29..32 from accC lanes 0..3
    const int x0f1 = (4 * (4 + L)) & 255;    // L0 combine: f1 lane 4+L
    const int x0f2 = (4 * (22 + L)) & 255;   //             f2 lane 22+L
    const int x0ti = (4 * (40 + L)) & 255;   //             ti lane 40+L
    const int x1f1 = (4 * L) & 255;
    const int x1f2 = (4 * (12 + L)) & 255;
    const int x1ti = (4 * (24 + L)) & 255;
    const int x2f1 = (4 * L) & 255;
    const int x2f2 = (4 * (3 + L)) & 255;
    const int x2ti = (4 * (6 + L)) & 255;

    // ---- state ----
    float h[33];
#pragma unroll
    for (int k = 0; k < 33; k++) h[k] = 0.f;
    float cc = 0.f;

    const float* Pb = P + (size_t)b * TSTEPS * NPAD;
    // 2-deep prefetch pipeline, 3 loads per lane per step
    float c1 = Pb[L], c2 = Pb[64 + L], c3 = Pb[128 + L];
    const float* P1 = Pb + NPAD;
    float n1 = P1[L], n2 = P1[64 + L], n3 = P1[128 + L];
    float* outp = out + (size_t)b * TSTEPS * 3 + L;

#pragma unroll 1
    for (int t = 0; t < TSTEPS; t++) {
        const int tf = (t + 2 < TSTEPS) ? t + 2 : TSTEPS - 1;
        const float* Pf = Pb + (size_t)tf * NPAD;
        const float f1p = Pf[L], f2p = Pf[64 + L], f3p = Pf[128 + L];

        // ---- Phase G: 132 gate dots, even/odd split chains ----
        float aA0 = c1, aA1 = 0.f, aB0 = c2, aB1 = 0.f, aC0 = c3, aC1 = 0.f;
#pragma unroll
        for (int k = 0; k < 32; k += 2) {
            aA0 = fmaf(wA[k],     h[k],     aA0);
            aA1 = fmaf(wA[k + 1], h[k + 1], aA1);
            aB0 = fmaf(wB[k],     h[k],     aB0);
            aB1 = fmaf(wB[k + 1], h[k + 1], aB1);
            aC0 = fmaf(wCt[k * 4 + jC],       h[k],     aC0);
            aC1 = fmaf(wCt[(k + 1) * 4 + jC], h[k + 1], aC1);
        }
        aA0 = fmaf(wA[32], h[32], aA0);
        aB0 = fmaf(wB[32], h[32], aB0);
        aC0 = fmaf(wCt[32 * 4 + jC], h[32], aC0);
        const float actA = actf(aA0 + aA1, sA, 0.f, aA, bA);
        const float actB = actf(aB0 + aB1, -L2E, scB, 1.f, 0.f);
        const float actC = actf(aC0 + aC1, -L2E, 0.f, 1.f, 0.f);
        const float gIgA = bperm(xIgA, actA);
        const float gIgB = bperm(xIgB, actB);
        const float gFg  = bperm(xFg, actB);
        const float gOgA = bperm(xOgA, actB);
        const float gOgC = bperm(xOgC, actC);
        const float IG = (L < 31) ? gIgA : gIgB;
        const float OG = (L < 29) ? gOgA : gOgC;
        cc = fmaf(cc, gFg, actA * IG);
        const float hv = actf(cc, -T2E, 0.f, 2.f, -1.f) * OG;

        // broadcast LSTM h
#pragma unroll
        for (int k = 0; k < 33; k++) h[k] = rl(hv, k);

        // ---- Phase L0: 54 dots (len 18) on lanes 4..57, single loop ----
        float l00 = c3, l01 = 0.f;
#pragma unroll
        for (int k = 0; k < 18; k += 2) {
            l00 = fmaf(w0[k],     h[k],     l00);
            l01 = fmaf(w0[k + 1], h[k + 1], l01);
        }
        {
            const float av = actf(l00 + l01, s0, 0.f, a0c, b0c);
            const float f1 = bperm(x0f1, av);
            const float f2 = bperm(x0f2, av);
            const float ti = bperm(x0ti, av);
            const float h0 = fmaf(ti, f2 - f1, f1);   // valid lanes 0..17
#pragma unroll
            for (int k = 0; k < 18; k++) h[k] = rl(h0, k);
        }

        // ---- Phase L1: 36 dots (len 30) on lanes 0..35, xc1 = h[0..29] ----
        float l10 = bias1, l11 = 0.f;
#pragma unroll
        for (int k = 0; k < 30; k += 2) {
            l10 = fmaf(w1[k],     h[k],     l10);
            l11 = fmaf(w1[k + 1], h[k + 1], l11);
        }
        {
            const float av = actf(l10 + l11, s1, 0.f, a1c, b1c);
            const float f1 = bperm(x1f1, av);
            const float f2 = bperm(x1f2, av);
            const float ti = bperm(x1ti, av);
            const float h1 = fmaf(ti, f2 - f1, f1);   // valid lanes 0..11
#pragma unroll
            for (int k = 0; k < 12; k++) h[18 + k] = rl(h1, k);
        }

        // ---- Phase L2: 9 dots (len 15) on lanes 0..8, xc2 = h[18..32] ----
        float l20 = bias2, l21 = 0.f;
#pragma unroll
        for (int k = 0; k < 14; k += 2) {
            l20 = fmaf(w2[k],     h[18 + k],     l20);
            l21 = fmaf(w2[k + 1], h[18 + k + 1], l21);
        }
        l20 = fmaf(w2[14], h[32], l20);
        {
            const float av = actf(l20 + l21, s2, 0.f, a2c, b2c);
            const float f1 = bperm(x2f1, av);
            const float f2 = bperm(x2f2, av);
            const float ti = bperm(x2ti, av);
            const float h2 = fmaf(ti, f2 - f1, f1);   // valid lanes 0..2
            if (L < 3) outp[(size_t)t * 3] = h2;
            h[30] = rl(h2, 0); h[31] = rl(h2, 1); h[32] = rl(h2, 2);
        }

        c1 = n1; c2 = n2; c3 = n3;
        n1 = f1p; n2 = f2p; n3 = f3p;
    }
}

// ---------------------------------------------------------------------------
extern "C" void kernel_launch(void* const* d_in, const int* in_sizes, int n_in,
                              void* d_out, int out_size, void* d_ws, size_t ws_size,
                              hipStream_t stream) {
    const float* x       = (const float*)d_in[0];
    const float* fc1_w   = (const float*)d_in[1];
    const float* fc1_b   = (const float*)d_in[2];
    const float* lstm_wi = (const float*)d_in[3];
    const float* lstm_bi = (const float*)d_in[4];
    const float* lstm_wh = (const float*)d_in[5];
    const float* ff1w0 = (const float*)d_in[6];
    const float* ff2w0 = (const float*)d_in[7];
    const float* taw0  = (const float*)d_in[8];
    const float* tbw0  = (const float*)d_in[9];
    const float* ff1b0 = (const float*)d_in[10];
    const float* ff2b0 = (const float*)d_in[11];
    const float* tab0  = (const float*)d_in[12];
    const float* tbb0  = (const float*)d_in[13];
    const float* ff1w1 = (const float*)d_in[14];
    const float* ff2w1 = (const float*)d_in[15];
    const float* taw1  = (const float*)d_in[16];
    const float* tbw1  = (const float*)d_in[17];
    const float* ff1b1 = (const float*)d_in[18];
    const float* ff2b1 = (const float*)d_in[19];
    const float* tab1  = (const float*)d_in[20];
    const float* tbb1  = (const float*)d_in[21];
    const float* ff1w2 = (const float*)d_in[22];
    const float* ff2w2 = (const float*)d_in[23];
    const float* taw2  = (const float*)d_in[24];
    const float* tbw2  = (const float*)d_in[25];
    const float* ff1b2 = (const float*)d_in[26];
    const float* ff2b2 = (const float*)d_in[27];
    const float* tab2  = (const float*)d_in[28];
    const float* tbb2  = (const float*)d_in[29];
    const float* mask0 = (const float*)d_in[30];
    const float* mask1 = (const float*)d_in[31];
    const float* mask2 = (const float*)d_in[32];

    float* Wc = (float*)d_ws;            // 512*192 floats
    float* bc = Wc + 512 * NW;           // 192 floats
    float* P  = bc + NW;                 // 32768*192 floats (~25.2 MB)
    float* outp = (float*)d_out;

    fold_kernel<<<192, 256, 0, stream>>>(fc1_w, fc1_b, lstm_wi, lstm_bi,
                                         ff1w0, ff2w0, taw0, tbw0,
                                         ff1b0, ff2b0, tab0, tbb0, mask0, Wc, bc);
    gemm_kernel<<<dim3(BT / 64, 3), 256, 0, stream>>>(x, Wc, bc, P);
    scan_kernel<<<NBATCH, 64, 0, stream>>>(P, lstm_wh,
                                           ff1w0, ff2w0, taw0, tbw0,
                                           ff1w1, ff2w1, taw1, tbw1,
                                           ff1b1, ff2b1, tab1, tbb1,
                                           ff1w2, ff2w2, taw2, tbw2,
                                           ff1b2, ff2b2, tab2, tbb2,
                                           mask1, mask2, outp);
}

// Round 7
// 621.539 us; speedup vs baseline: 1.2379x; 1.1026x over previous
//
#include <hip/hip_runtime.h>
#include <hip/hip_bf16.h>

// Problem constants
#define BT 32768      // B*T = 64*512
#define TSTEPS 512
#define NBATCH 64
#define KDIM 512      // IN_DIM
#define NPAD 192      // P row stride == logical cols (132 z + 54 l0 + 6 pad)
#define NW 192        // Wc cols

#define L2E 1.4426950408889634f
#define T2E 2.8853900817779268f

__device__ __forceinline__ float rl(float v, int lane) {
    return __int_as_float(__builtin_amdgcn_readlane(__float_as_int(v), lane));
}
__device__ __forceinline__ float bperm(int byteidx, float v) {
    return __int_as_float(__builtin_amdgcn_ds_bpermute(byteidx, __float_as_int(v)));
}
// unified activation: a * rcp(1 + exp2(s*x + sc)) + b
__device__ __forceinline__ float actf(float x, float s, float sc, float a, float b) {
    float e = exp2f(fmaf(s, x, sc));
    return fmaf(a, __builtin_amdgcn_rcpf(1.f + e), b);
}

// ---------------------------------------------------------------------------
// Kernel 1: fold fc1 into the stacked scan-input projection.
// Column o (identity layout):
//   o in [0,132):   z dot o (gate g=o/33, neuron i=o%33): lstm_wi row o
//   o in [132,186): L0 dot e=o-132, e=m*18+i, m in {ff1,ff2,ta+tb merged}
//   o in [186,192): zero pad
// ---------------------------------------------------------------------------
__global__ __launch_bounds__(256) void fold_kernel(
    const float* __restrict__ fc1_w, const float* __restrict__ fc1_b,
    const float* __restrict__ lstm_wi, const float* __restrict__ lstm_bi,
    const float* __restrict__ ff1w0, const float* __restrict__ ff2w0,
    const float* __restrict__ taw0, const float* __restrict__ tbw0,
    const float* __restrict__ ff1b0, const float* __restrict__ ff2b0,
    const float* __restrict__ tab0, const float* __restrict__ tbb0,
    const float* __restrict__ mask0,
    float* __restrict__ Wc, float* __restrict__ bc)
{
    const int o = blockIdx.x;   // 0..191
    const int t = threadIdx.x;  // 0..255 = latent index l
    __shared__ float wrow[256];
    __shared__ float red[256];

    float wl = 0.f, b0 = 0.f;
    if (o < 132) { wl = lstm_wi[o * 256 + t]; b0 = lstm_bi[o]; }
    else if (o < 186) {
        const int e = o - 132, m = e / 18, i = e - m * 18;
        if (m == 0)      { wl = ff1w0[i * 274 + t] * mask0[i * 274 + t]; b0 = ff1b0[i]; }
        else if (m == 1) { wl = ff2w0[i * 274 + t] * mask0[i * 274 + t]; b0 = ff2b0[i]; }
        else             { wl = taw0[i * 274 + t] + tbw0[i * 274 + t];   b0 = tab0[i] + tbb0[i]; }
    }
    wrow[t] = wl;
    __syncthreads();

    float acc0 = 0.f, acc1 = 0.f;
    for (int l = 0; l < 256; l++) {
        float w = wrow[l];
        acc0 = fmaf(fc1_w[l * 512 + t], w, acc0);
        acc1 = fmaf(fc1_w[l * 512 + t + 256], w, acc1);
    }
    Wc[(size_t)t * NW + o] = acc0;
    Wc[(size_t)(t + 256) * NW + o] = acc1;

    red[t] = fc1_b[t] * wl;
    __syncthreads();
    for (int s = 128; s > 0; s >>= 1) {
        if (t < s) red[t] += red[t + s];
        __syncthreads();
    }
    if (t == 0) bc[o] = red[0] + b0;
}

// ---------------------------------------------------------------------------
// Kernel 2: P[m][n] = sum_k X[m][k]*Wc[k][n] + bc[n], fp32 LDS-tiled GEMM.
// M=32768, K=512, N=192. Tile 64x64x16, grid (512, 3).
// ---------------------------------------------------------------------------
__global__ __launch_bounds__(256) void gemm_kernel(
    const float* __restrict__ X, const float* __restrict__ Wc,
    const float* __restrict__ bc, float* __restrict__ P)
{
    __shared__ float As[16][68];
    __shared__ float Bs[16][64];
    const int tid = threadIdx.x;
    const int m0 = blockIdx.x * 64;
    const int n0 = blockIdx.y * 64;
    const int lr = tid >> 2;
    const int lc = (tid & 3) << 2;
    const int wr = tid >> 4;
    const int wc = (tid & 15) << 2;
    const int tm = (tid >> 4) << 2;
    const int tn = (tid & 15) << 2;

    float acc[4][4];
#pragma unroll
    for (int i = 0; i < 4; i++)
#pragma unroll
        for (int j = 0; j < 4; j++) acc[i][j] = 0.f;

    for (int k0 = 0; k0 < KDIM; k0 += 16) {
        float4 av = *(const float4*)(X + (size_t)(m0 + lr) * KDIM + k0 + lc);
        float4 bv = *(const float4*)(Wc + (size_t)(k0 + wr) * NW + n0 + wc);
        __syncthreads();
        As[lc + 0][lr] = av.x; As[lc + 1][lr] = av.y;
        As[lc + 2][lr] = av.z; As[lc + 3][lr] = av.w;
        *(float4*)&Bs[wr][wc] = bv;
        __syncthreads();
#pragma unroll
        for (int k = 0; k < 16; k++) {
            float4 a = *(const float4*)&As[k][tm];
            float4 b = *(const float4*)&Bs[k][tn];
            acc[0][0] = fmaf(a.x, b.x, acc[0][0]); acc[0][1] = fmaf(a.x, b.y, acc[0][1]);
            acc[0][2] = fmaf(a.x, b.z, acc[0][2]); acc[0][3] = fmaf(a.x, b.w, acc[0][3]);
            acc[1][0] = fmaf(a.y, b.x, acc[1][0]); acc[1][1] = fmaf(a.y, b.y, acc[1][1]);
            acc[1][2] = fmaf(a.y, b.z, acc[1][2]); acc[1][3] = fmaf(a.y, b.w, acc[1][3]);
            acc[2][0] = fmaf(a.z, b.x, acc[2][0]); acc[2][1] = fmaf(a.z, b.y, acc[2][1]);
            acc[2][2] = fmaf(a.z, b.z, acc[2][2]); acc[2][3] = fmaf(a.z, b.w, acc[2][3]);
            acc[3][0] = fmaf(a.w, b.x, acc[3][0]); acc[3][1] = fmaf(a.w, b.y, acc[3][1]);
            acc[3][2] = fmaf(a.w, b.z, acc[3][2]); acc[3][3] = fmaf(a.w, b.w, acc[3][3]);
        }
    }

    {
        float4 bias = *(const float4*)(bc + n0 + tn);
#pragma unroll
        for (int i = 0; i < 4; i++) {
            float4 r;
            r.x = acc[i][0] + bias.x; r.y = acc[i][1] + bias.y;
            r.z = acc[i][2] + bias.z; r.w = acc[i][3] + bias.w;
            *(float4*)(P + (size_t)(m0 + tm + i) * NPAD + n0 + tn) = r;
        }
    }
}

// ---------------------------------------------------------------------------
// Kernel 3: persistent scan, one wave per batch element.
// Cross-phase pipelined: the 33-term gate dots for step t+1 are accumulated
// incrementally as each carry segment (L0out/L1out/L2out) is broadcast during
// step t, so at loop top the gate pre-activations are ALREADY complete.
// L1/L2's LSTM-h partial dots are likewise hoisted off the critical path.
// ---------------------------------------------------------------------------
__global__ __launch_bounds__(64)
__attribute__((amdgpu_waves_per_eu(1, 1)))
void scan_kernel(
    const float* __restrict__ P, const float* __restrict__ lstm_wh,
    const float* __restrict__ ff1w0, const float* __restrict__ ff2w0,
    const float* __restrict__ taw0, const float* __restrict__ tbw0,
    const float* __restrict__ ff1w1, const float* __restrict__ ff2w1,
    const float* __restrict__ taw1, const float* __restrict__ tbw1,
    const float* __restrict__ ff1b1, const float* __restrict__ ff2b1,
    const float* __restrict__ tab1, const float* __restrict__ tbb1,
    const float* __restrict__ ff1w2, const float* __restrict__ ff2w2,
    const float* __restrict__ taw2, const float* __restrict__ tbw2,
    const float* __restrict__ ff1b2, const float* __restrict__ ff2b2,
    const float* __restrict__ tab2, const float* __restrict__ tbb2,
    const float* __restrict__ mask1, const float* __restrict__ mask2,
    float* __restrict__ out)
{
    const int L = threadIdx.x;
    const int b = blockIdx.x;

    // LDS copy of the 4 straggler z rows (dots 128..131), transposed
    __shared__ float wCt[33 * 4];    // wCt[k*4+j] = lstm_wh[(128+j)*33+k]
    if (L < 33) {
        for (int j = 0; j < 4; j++) wCt[L * 4 + j] = lstm_wh[(128 + j) * 33 + L];
    }
    __syncthreads();
    const int jC = L & 3;

    // ---- G weights: rows L, 64+L of stacked [132][33] lstm_wh ----
    float wA[33], wB[33];
#pragma unroll
    for (int k = 0; k < 33; k++) {
        wA[k] = lstm_wh[L * 33 + k];
        wB[k] = lstm_wh[(64 + L) * 33 + k];
    }
    // ---- L0 weights: dot e=L-4 (clamped), m=e/18; ta+tb merged ----
    float w0[18];
    {
        int e = L - 4; e = (e < 0) ? 0 : ((e > 53) ? 53 : e);
        const int m = e / 18, i = e - m * 18;
        const float* pa = (m == 0) ? ff1w0 : (m == 1) ? ff2w0 : taw0;
#pragma unroll
        for (int k = 0; k < 18; k++) {
            float w = pa[i * 274 + 256 + k];
            if (m == 2) w += tbw0[i * 274 + 256 + k];
            w0[k] = w;
        }
    }
    // ---- L1 weights: dot d=m*12+i on lanes 0..35 ----
    float w1[30], bias1;
    {
        const int d = (L < 36) ? L : 35;
        const int m = d / 12, i = d - m * 12;
        const float* pa = (m == 0) ? ff1w1 : (m == 1) ? ff2w1 : taw1;
#pragma unroll
        for (int k = 0; k < 30; k++) {
            float w = pa[i * 30 + k];
            if (m == 2) w += tbw1[i * 30 + k];
            else w *= mask1[i * 30 + k];
            w1[k] = w;
        }
        bias1 = (m == 0) ? ff1b1[i] : (m == 1) ? ff2b1[i] : (tab1[i] + tbb1[i]);
    }
    // ---- L2 weights: dot d=m*3+i on lanes 0..8 ----
    float w2[15], bias2;
    {
        const int d = (L < 9) ? L : 8;
        const int m = d / 3, i = d - m * 3;
        const float* pa = (m == 0) ? ff1w2 : (m == 1) ? ff2w2 : taw2;
#pragma unroll
        for (int k = 0; k < 15; k++) {
            float w = pa[i * 15 + k];
            if (m == 2) w += tbw2[i * 15 + k];
            else w *= mask2[i * 15 + k];
            w2[k] = w;
        }
        bias2 = (m == 0) ? ff1b2[i] : (m == 1) ? ff2b2[i] : (tab2[i] + tbb2[i]);
    }

    // ---- per-lane activation constants ----
    const float sA  = (L < 33) ? -T2E : -L2E;           // accA: ia tanh, ig sig
    const float aA  = (L < 33) ? 2.f : 1.f;
    const float bA  = (L < 33) ? -1.f : 0.f;
    const float scB = (L >= 2 && L <= 34) ? -L2E : 0.f; // accB: fg gets sig(x+1)
    const float s0  = (L < 40) ? -T2E : -L2E;           // L0 act: 4..39 tanh, 40..57 sig
    const float a0c = (L < 40) ? 2.f : 1.f;
    const float b0c = (L < 40) ? -1.f : 0.f;
    const float s1  = (L < 24) ? -T2E : -L2E;           // L1: 0..23 tanh, 24..35 sig
    const float a1c = (L < 24) ? 2.f : 1.f;
    const float b1c = (L < 24) ? -1.f : 0.f;
    const float s2  = (L < 6) ? -T2E : -L2E;            // L2: 0..5 tanh, 6..8 sig
    const float a2c = (L < 6) ? 2.f : 1.f;
    const float b2c = (L < 6) ? -1.f : 0.f;

    // ---- per-lane bpermute byte indices ----
    const int xIgA = (4 * (33 + L)) & 255;
    const int xIgB = (4 * (L - 31)) & 255;
    const int xFg  = (4 * (2 + L)) & 255;
    const int xOgA = (4 * (35 + L)) & 255;
    const int xOgC = (4 * (L - 29)) & 255;
    const int x0f1 = (4 * (4 + L)) & 255;
    const int x0f2 = (4 * (22 + L)) & 255;
    const int x0ti = (4 * (40 + L)) & 255;
    const int x1f1 = (4 * L) & 255;
    const int x1f2 = (4 * (12 + L)) & 255;
    const int x1ti = (4 * (24 + L)) & 255;
    const int x2f1 = (4 * L) & 255;
    const int x2f2 = (4 * (3 + L)) & 255;
    const int x2ti = (4 * (6 + L)) & 255;

    // ---- state ----
    float h[33];
#pragma unroll
    for (int k = 0; k < 33; k++) h[k] = 0.f;
    float cc = 0.f;

    const float* Pb = P + (size_t)b * TSTEPS * NPAD;
    float c3 = Pb[128 + L];
    const float* P1 = Pb + NPAD;
    float n1 = P1[L], n2 = P1[64 + L], n3 = P1[128 + L];
    // gate pre-activations for step 0 (h=0 -> pure precomp)
    float gA = Pb[L], gB = Pb[64 + L], gC = c3;
    float* outp = out + (size_t)b * TSTEPS * 3 + L;

#pragma unroll 1
    for (int t = 0; t < TSTEPS; t++) {
        const int tf = (t + 2 < TSTEPS) ? t + 2 : TSTEPS - 1;
        const float* Pf = Pb + (size_t)tf * NPAD;
        const float f1p = Pf[L], f2p = Pf[64 + L], f3p = Pf[128 + L];

        // ---- Phase G: gate dots ALREADY complete in gA/gB/gC ----
        const float actA = actf(gA, sA, 0.f, aA, bA);
        const float actB = actf(gB, -L2E, scB, 1.f, 0.f);
        const float actC = actf(gC, -L2E, 0.f, 1.f, 0.f);
        const float gIgA = bperm(xIgA, actA);
        const float gIgB = bperm(xIgB, actB);
        const float gFg  = bperm(xFg, actB);
        const float gOgA = bperm(xOgA, actB);
        const float gOgC = bperm(xOgC, actC);
        const float IG = (L < 31) ? gIgA : gIgB;
        const float OG = (L < 29) ? gOgA : gOgC;
        cc = fmaf(cc, gFg, actA * IG);
        const float hv = actf(cc, -T2E, 0.f, 2.f, -1.f) * OG;

        // broadcast LSTM h (inter first: L0's dot is on the critical path)
#pragma unroll
        for (int k = 0; k < 18; k++) h[k] = rl(hv, k);

        // ---- Phase L0: 54 dots (len 18), 4-way split (on critical path) ----
        float A0 = c3, A1 = 0.f, A2 = 0.f, A3 = 0.f;
#pragma unroll
        for (int k = 0; k < 16; k += 4) {
            A0 = fmaf(w0[k],     h[k],     A0);
            A1 = fmaf(w0[k + 1], h[k + 1], A1);
            A2 = fmaf(w0[k + 2], h[k + 2], A2);
            A3 = fmaf(w0[k + 3], h[k + 3], A3);
        }
        A0 = fmaf(w0[16], h[16], A0);
        A1 = fmaf(w0[17], h[17], A1);
        const float l0 = (A0 + A1) + (A2 + A3);

        // off-path: rest of hv broadcast + L1/L2 LSTM-h partial dots
#pragma unroll
        for (int k = 18; k < 33; k++) h[k] = rl(hv, k);
        float l1p = bias1;
#pragma unroll
        for (int k = 18; k < 30; k++) l1p = fmaf(w1[k], h[k], l1p);
        float l2p = bias2;
        l2p = fmaf(w2[12], h[30], l2p);
        l2p = fmaf(w2[13], h[31], l2p);
        l2p = fmaf(w2[14], h[32], l2p);

        // L0 combine
        {
            const float av = actf(l0, s0, 0.f, a0c, b0c);
            const float f1 = bperm(x0f1, av);
            const float f2 = bperm(x0f2, av);
            const float ti = bperm(x0ti, av);
            const float h0 = fmaf(ti, f2 - f1, f1);   // valid lanes 0..17
#pragma unroll
            for (int k = 0; k < 18; k++) h[k] = rl(h0, k);
        }

        // ---- seed next-step gate dots: inter segment (off critical path) ----
        gA = n1; gB = n2; gC = n3;
#pragma unroll
        for (int k = 0; k < 18; k++) {
            gA = fmaf(wA[k], h[k], gA);
            gB = fmaf(wB[k], h[k], gB);
            gC = fmaf(wCt[k * 4 + jC], h[k], gC);
        }

        // ---- Phase L1 residual: 18 terms over L0out, 4-way (on path) ----
        float B0 = l1p, B1 = 0.f, B2 = 0.f, B3 = 0.f;
#pragma unroll
        for (int k = 0; k < 16; k += 4) {
            B0 = fmaf(w1[k],     h[k],     B0);
            B1 = fmaf(w1[k + 1], h[k + 1], B1);
            B2 = fmaf(w1[k + 2], h[k + 2], B2);
            B3 = fmaf(w1[k + 3], h[k + 3], B3);
        }
        B0 = fmaf(w1[16], h[16], B0);
        B1 = fmaf(w1[17], h[17], B1);
        const float l1 = (B0 + B1) + (B2 + B3);
        {
            const float av = actf(l1, s1, 0.f, a1c, b1c);
            const float f1 = bperm(x1f1, av);
            const float f2 = bperm(x1f2, av);
            const float ti = bperm(x1ti, av);
            const float h1 = fmaf(ti, f2 - f1, f1);   // valid lanes 0..11
#pragma unroll
            for (int k = 0; k < 12; k++) h[18 + k] = rl(h1, k);
        }

        // ---- gate dots: command segment (off path) ----
#pragma unroll
        for (int k = 18; k < 30; k++) {
            gA = fmaf(wA[k], h[k], gA);
            gB = fmaf(wB[k], h[k], gB);
            gC = fmaf(wCt[k * 4 + jC], h[k], gC);
        }

        // ---- Phase L2 residual: 12 terms over L1out, 4-way (on path) ----
        float C0 = l2p, C1 = 0.f, C2 = 0.f, C3 = 0.f;
#pragma unroll
        for (int k = 0; k < 12; k += 4) {
            C0 = fmaf(w2[k],     h[18 + k],     C0);
            C1 = fmaf(w2[k + 1], h[18 + k + 1], C1);
            C2 = fmaf(w2[k + 2], h[18 + k + 2], C2);
            C3 = fmaf(w2[k + 3], h[18 + k + 3], C3);
        }
        const float l2 = (C0 + C1) + (C2 + C3);
        {
            const float av = actf(l2, s2, 0.f, a2c, b2c);
            const float f1 = bperm(x2f1, av);
            const float f2 = bperm(x2f2, av);
            const float ti = bperm(x2ti, av);
            const float h2 = fmaf(ti, f2 - f1, f1);   // valid lanes 0..2
            if (L < 3) outp[(size_t)t * 3] = h2;
            h[30] = rl(h2, 0); h[31] = rl(h2, 1); h[32] = rl(h2, 2);
        }

        // ---- gate dots: motor segment (short, trailing) ----
#pragma unroll
        for (int k = 30; k < 33; k++) {
            gA = fmaf(wA[k], h[k], gA);
            gB = fmaf(wB[k], h[k], gB);
            gC = fmaf(wCt[k * 4 + jC], h[k], gC);
        }

        // rotate prefetch pipeline
        c3 = n3;
        n1 = f1p; n2 = f2p; n3 = f3p;
    }
}

// ---------------------------------------------------------------------------
extern "C" void kernel_launch(void* const* d_in, const int* in_sizes, int n_in,
                              void* d_out, int out_size, void* d_ws, size_t ws_size,
                              hipStream_t stream) {
    const float* x       = (const float*)d_in[0];
    const float* fc1_w   = (const float*)d_in[1];
    const float* fc1_b   = (const float*)d_in[2];
    const float* lstm_wi = (const float*)d_in[3];
    const float* lstm_bi = (const float*)d_in[4];
    const float* lstm_wh = (const float*)d_in[5];
    const float* ff1w0 = (const float*)d_in[6];
    const float* ff2w0 = (const float*)d_in[7];
    const float* taw0  = (const float*)d_in[8];
    const float* tbw0  = (const float*)d_in[9];
    const float* ff1b0 = (const float*)d_in[10];
    const float* ff2b0 = (const float*)d_in[11];
    const float* tab0  = (const float*)d_in[12];
    const float* tbb0  = (const float*)d_in[13];
    const float* ff1w1 = (const float*)d_in[14];
    const float* ff2w1 = (const float*)d_in[15];
    const float* taw1  = (const float*)d_in[16];
    const float* tbw1  = (const float*)d_in[17];
    const float* ff1b1 = (const float*)d_in[18];
    const float* ff2b1 = (const float*)d_in[19];
    const float* tab1  = (const float*)d_in[20];
    const float* tbb1  = (const float*)d_in[21];
    const float* ff1w2 = (const float*)d_in[22];
    const float* ff2w2 = (const float*)d_in[23];
    const float* taw2  = (const float*)d_in[24];
    const float* tbw2  = (const float*)d_in[25];
    const float* ff1b2 = (const float*)d_in[26];
    const float* ff2b2 = (const float*)d_in[27];
    const float* tab2  = (const float*)d_in[28];
    const float* tbb2  = (const float*)d_in[29];
    const float* mask0 = (const float*)d_in[30];
    const float* mask1 = (const float*)d_in[31];
    const float* mask2 = (const float*)d_in[32];

    float* Wc = (float*)d_ws;            // 512*192 floats
    float* bc = Wc + 512 * NW;           // 192 floats
    float* P  = bc + NW;                 // 32768*192 floats (~25.2 MB)
    float* outp = (float*)d_out;

    fold_kernel<<<192, 256, 0, stream>>>(fc1_w, fc1_b, lstm_wi, lstm_bi,
                                         ff1w0, ff2w0, taw0, tbw0,
                                         ff1b0, ff2b0, tab0, tbb0, mask0, Wc, bc);
    gemm_kernel<<<dim3(BT / 64, 3), 256, 0, stream>>>(x, Wc, bc, P);
    scan_kernel<<<NBATCH, 64, 0, stream>>>(P, lstm_wh,
                                           ff1w0, ff2w0, taw0, tbw0,
                                           ff1w1, ff2w1, taw1, tbw1,
                                           ff1b1, ff2b1, tab1, tbb1,
                                           ff1w2, ff2w2, taw2, tbw2,
                                           ff1b2, ff2b2, tab2, tbb2,
                                           mask1, mask2, outp);
}

// Round 8
// 615.071 us; speedup vs baseline: 1.2509x; 1.0105x over previous
//
#include <hip/hip_runtime.h>
#include <hip/hip_bf16.h>

// Problem constants
#define BT 32768      // B*T = 64*512
#define TSTEPS 512
#define NBATCH 64
#define KDIM 512      // IN_DIM
#define NPAD 192      // P row stride
#define NW 192        // Wc cols

#define L2E 1.4426950408889634f
#define T2E 2.8853900817779268f

__device__ __forceinline__ float rl(float v, int lane) {
    return __int_as_float(__builtin_amdgcn_readlane(__float_as_int(v), lane));
}
__device__ __forceinline__ float bperm(int byteidx, float v) {
    return __int_as_float(__builtin_amdgcn_ds_bpermute(byteidx, __float_as_int(v)));
}
// unified activation: a * rcp(1 + exp2(s*x + sc)) + b
__device__ __forceinline__ float actf(float x, float s, float sc, float a, float b) {
    float e = exp2f(fmaf(s, x, sc));
    return fmaf(a, __builtin_amdgcn_rcpf(1.f + e), b);
}

// P column layout (scan-friendly):
//   z dot (gate g, neuron i) -> col 4*i+g   (cols 0..131; lane i reads float4 @ 4i)
//   L0 dot e -> col 132+e                   (cols 132..185; lane 4+e reads scalar)
//   cols 186..191 pad (zero)
__device__ __forceinline__ int permpos(int o) {
    if (o < 132) { int g = o / 33, i = o - g * 33; return 4 * i + g; }
    return o;
}

// ---------------------------------------------------------------------------
// Kernel 1: fold fc1 into the stacked scan-input projection (permuted cols).
// ---------------------------------------------------------------------------
__global__ __launch_bounds__(256) void fold_kernel(
    const float* __restrict__ fc1_w, const float* __restrict__ fc1_b,
    const float* __restrict__ lstm_wi, const float* __restrict__ lstm_bi,
    const float* __restrict__ ff1w0, const float* __restrict__ ff2w0,
    const float* __restrict__ taw0, const float* __restrict__ tbw0,
    const float* __restrict__ ff1b0, const float* __restrict__ ff2b0,
    const float* __restrict__ tab0, const float* __restrict__ tbb0,
    const float* __restrict__ mask0,
    float* __restrict__ Wc, float* __restrict__ bc)
{
    const int o = blockIdx.x;   // 0..191 logical column
    const int t = threadIdx.x;  // 0..255 = latent index l
    const int p = permpos(o);
    __shared__ float wrow[256];
    __shared__ float red[256];

    float wl = 0.f, b0 = 0.f;
    if (o < 132) { wl = lstm_wi[o * 256 + t]; b0 = lstm_bi[o]; }
    else if (o < 186) {
        const int e = o - 132, m = e / 18, i = e - m * 18;
        if (m == 0)      { wl = ff1w0[i * 274 + t] * mask0[i * 274 + t]; b0 = ff1b0[i]; }
        else if (m == 1) { wl = ff2w0[i * 274 + t] * mask0[i * 274 + t]; b0 = ff2b0[i]; }
        else             { wl = taw0[i * 274 + t] + tbw0[i * 274 + t];   b0 = tab0[i] + tbb0[i]; }
    }
    wrow[t] = wl;
    __syncthreads();

    float acc0 = 0.f, acc1 = 0.f;
    for (int l = 0; l < 256; l++) {
        float w = wrow[l];
        acc0 = fmaf(fc1_w[l * 512 + t], w, acc0);
        acc1 = fmaf(fc1_w[l * 512 + t + 256], w, acc1);
    }
    Wc[(size_t)t * NW + p] = acc0;
    Wc[(size_t)(t + 256) * NW + p] = acc1;

    red[t] = fc1_b[t] * wl;
    __syncthreads();
    for (int s = 128; s > 0; s >>= 1) {
        if (t < s) red[t] += red[t + s];
        __syncthreads();
    }
    if (t == 0) bc[p] = red[0] + b0;
}

// ---------------------------------------------------------------------------
// Kernel 2: P[m][n] = sum_k X[m][k]*Wc[k][n] + bc[n], fp32 LDS-tiled GEMM.
// M=32768, K=512, N=192. Tile 64x64x16, grid (512, 3).
// ---------------------------------------------------------------------------
__global__ __launch_bounds__(256) void gemm_kernel(
    const float* __restrict__ X, const float* __restrict__ Wc,
    const float* __restrict__ bc, float* __restrict__ P)
{
    __shared__ float As[16][68];
    __shared__ float Bs[16][64];
    const int tid = threadIdx.x;
    const int m0 = blockIdx.x * 64;
    const int n0 = blockIdx.y * 64;
    const int lr = tid >> 2;
    const int lc = (tid & 3) << 2;
    const int wr = tid >> 4;
    const int wc = (tid & 15) << 2;
    const int tm = (tid >> 4) << 2;
    const int tn = (tid & 15) << 2;

    float acc[4][4];
#pragma unroll
    for (int i = 0; i < 4; i++)
#pragma unroll
        for (int j = 0; j < 4; j++) acc[i][j] = 0.f;

    for (int k0 = 0; k0 < KDIM; k0 += 16) {
        float4 av = *(const float4*)(X + (size_t)(m0 + lr) * KDIM + k0 + lc);
        float4 bv = *(const float4*)(Wc + (size_t)(k0 + wr) * NW + n0 + wc);
        __syncthreads();
        As[lc + 0][lr] = av.x; As[lc + 1][lr] = av.y;
        As[lc + 2][lr] = av.z; As[lc + 3][lr] = av.w;
        *(float4*)&Bs[wr][wc] = bv;
        __syncthreads();
#pragma unroll
        for (int k = 0; k < 16; k++) {
            float4 a = *(const float4*)&As[k][tm];
            float4 b = *(const float4*)&Bs[k][tn];
            acc[0][0] = fmaf(a.x, b.x, acc[0][0]); acc[0][1] = fmaf(a.x, b.y, acc[0][1]);
            acc[0][2] = fmaf(a.x, b.z, acc[0][2]); acc[0][3] = fmaf(a.x, b.w, acc[0][3]);
            acc[1][0] = fmaf(a.y, b.x, acc[1][0]); acc[1][1] = fmaf(a.y, b.y, acc[1][1]);
            acc[1][2] = fmaf(a.y, b.z, acc[1][2]); acc[1][3] = fmaf(a.y, b.w, acc[1][3]);
            acc[2][0] = fmaf(a.z, b.x, acc[2][0]); acc[2][1] = fmaf(a.z, b.y, acc[2][1]);
            acc[2][2] = fmaf(a.z, b.z, acc[2][2]); acc[2][3] = fmaf(a.z, b.w, acc[2][3]);
            acc[3][0] = fmaf(a.w, b.x, acc[3][0]); acc[3][1] = fmaf(a.w, b.y, acc[3][1]);
            acc[3][2] = fmaf(a.w, b.z, acc[3][2]); acc[3][3] = fmaf(a.w, b.w, acc[3][3]);
        }
    }

    {
        float4 bias = *(const float4*)(bc + n0 + tn);
#pragma unroll
        for (int i = 0; i < 4; i++) {
            float4 r;
            r.x = acc[i][0] + bias.x; r.y = acc[i][1] + bias.y;
            r.z = acc[i][2] + bias.z; r.w = acc[i][3] + bias.w;
            *(float4*)(P + (size_t)(m0 + tm + i) * NPAD + n0 + tn) = r;
        }
    }
}

// ---------------------------------------------------------------------------
// Kernel 3: persistent scan, one wave per batch element.
// NEURON-LOCAL LSTM: lane i holds all four gate accumulators (ia/ig/fg/og),
// fed by one ds_read_b128 per k from the packed LDS tile G4[k][i]. Phase G
// has NO cross-lane ops and no act-selects. Gate seeds for step t+1 are
// accumulated incrementally as carry segments broadcast (R7 pipelining).
// Register arrays: w0(18)+w1(30)+w2(15)+h(33) ~= 96 -> fits, no spills.
// ---------------------------------------------------------------------------
__global__ __launch_bounds__(64)
__attribute__((amdgpu_waves_per_eu(1, 1)))
void scan_kernel(
    const float* __restrict__ P, const float* __restrict__ lstm_wh,
    const float* __restrict__ ff1w0, const float* __restrict__ ff2w0,
    const float* __restrict__ taw0, const float* __restrict__ tbw0,
    const float* __restrict__ ff1w1, const float* __restrict__ ff2w1,
    const float* __restrict__ taw1, const float* __restrict__ tbw1,
    const float* __restrict__ ff1b1, const float* __restrict__ ff2b1,
    const float* __restrict__ tab1, const float* __restrict__ tbb1,
    const float* __restrict__ ff1w2, const float* __restrict__ ff2w2,
    const float* __restrict__ taw2, const float* __restrict__ tbw2,
    const float* __restrict__ ff1b2, const float* __restrict__ ff2b2,
    const float* __restrict__ tab2, const float* __restrict__ tbb2,
    const float* __restrict__ mask1, const float* __restrict__ mask2,
    float* __restrict__ out)
{
    const int L = threadIdx.x;
    const int b = blockIdx.x;

    // packed gate weights: G4[k*33+i] = (w_ia, w_ig, w_fg, w_og) for neuron i, term k
    __shared__ float4 G4[33 * 33];
    for (int idx = L; idx < 33 * 33; idx += 64) {
        const int k = idx / 33, i = idx - k * 33;
        float4 g;
        g.x = lstm_wh[i * 33 + k];
        g.y = lstm_wh[(33 + i) * 33 + k];
        g.z = lstm_wh[(66 + i) * 33 + k];
        g.w = lstm_wh[(99 + i) * 33 + k];
        G4[idx] = g;
    }
    __syncthreads();

    const int iG = (L < 33) ? L : 32;   // gate neuron (lanes 33..63 duplicate 32)

    // ---- L0 weights: dot e=L-4 (clamped), m=e/18; ta+tb merged ----
    float w0[18];
    {
        int e = L - 4; e = (e < 0) ? 0 : ((e > 53) ? 53 : e);
        const int m = e / 18, i = e - m * 18;
        const float* pa = (m == 0) ? ff1w0 : (m == 1) ? ff2w0 : taw0;
#pragma unroll
        for (int k = 0; k < 18; k++) {
            float w = pa[i * 274 + 256 + k];
            if (m == 2) w += tbw0[i * 274 + 256 + k];
            w0[k] = w;
        }
    }
    // ---- L1 weights: dot d=m*12+i on lanes 0..35 ----
    float w1[30], bias1;
    {
        const int d = (L < 36) ? L : 35;
        const int m = d / 12, i = d - m * 12;
        const float* pa = (m == 0) ? ff1w1 : (m == 1) ? ff2w1 : taw1;
#pragma unroll
        for (int k = 0; k < 30; k++) {
            float w = pa[i * 30 + k];
            if (m == 2) w += tbw1[i * 30 + k];
            else w *= mask1[i * 30 + k];
            w1[k] = w;
        }
        bias1 = (m == 0) ? ff1b1[i] : (m == 1) ? ff2b1[i] : (tab1[i] + tbb1[i]);
    }
    // ---- L2 weights: dot d=m*3+i on lanes 0..8 ----
    float w2[15], bias2;
    {
        const int d = (L < 9) ? L : 8;
        const int m = d / 3, i = d - m * 3;
        const float* pa = (m == 0) ? ff1w2 : (m == 1) ? ff2w2 : taw2;
#pragma unroll
        for (int k = 0; k < 15; k++) {
            float w = pa[i * 15 + k];
            if (m == 2) w += tbw2[i * 15 + k];
            else w *= mask2[i * 15 + k];
            w2[k] = w;
        }
        bias2 = (m == 0) ? ff1b2[i] : (m == 1) ? ff2b2[i] : (tab2[i] + tbb2[i]);
    }

    // ---- per-lane activation constants (layers only) ----
    const float s0  = (L < 40) ? -T2E : -L2E;   // L0: lanes 4..39 tanh, 40..57 sig
    const float a0c = (L < 40) ? 2.f : 1.f;
    const float b0c = (L < 40) ? -1.f : 0.f;
    const float s1  = (L < 24) ? -T2E : -L2E;
    const float a1c = (L < 24) ? 2.f : 1.f;
    const float b1c = (L < 24) ? -1.f : 0.f;
    const float s2  = (L < 6) ? -T2E : -L2E;
    const float a2c = (L < 6) ? 2.f : 1.f;
    const float b2c = (L < 6) ? -1.f : 0.f;

    // ---- per-lane bpermute byte indices (layer combines) ----
    const int x0f1 = (4 * (4 + L)) & 255;
    const int x0f2 = (4 * (22 + L)) & 255;
    const int x0ti = (4 * (40 + L)) & 255;
    const int x1f1 = (4 * L) & 255;
    const int x1f2 = (4 * (12 + L)) & 255;
    const int x1ti = (4 * (24 + L)) & 255;
    const int x2f1 = (4 * L) & 255;
    const int x2f2 = (4 * (3 + L)) & 255;
    const int x2ti = (4 * (6 + L)) & 255;

    // ---- state ----
    float h[33];
#pragma unroll
    for (int k = 0; k < 33; k++) h[k] = 0.f;
    float cc = 0.f;

    // per-lane P addresses: z float4 @ col 4*iG; L0 scalar @ col 128+clamp(L,4,57)
    const float* Pb = P + (size_t)b * TSTEPS * NPAD;
    int Lc = L; if (Lc < 4) Lc = 4; if (Lc > 57) Lc = 57;
    const float* pzp = Pb + 4 * iG;
    const float* plp = Pb + 128 + Lc;

    // step-0 seeds (carry = 0 -> pure precomp) and step-0 L0 precomp
    float4 z0 = *(const float4*)pzp;
    float zA = z0.x, zB = z0.y, zC = z0.z, zD = z0.w;
    float curl0 = *plp;
    // prefetch step-1
    float4 nz4 = *(const float4*)(pzp + NPAD);
    float nl0 = *(plp + NPAD);

    float* outp = out + (size_t)b * TSTEPS * 3 + L;

#pragma unroll 1
    for (int t = 0; t < TSTEPS; t++) {
        // issue loads for step t+2
        const int df = (t + 2 < TSTEPS) ? (t + 2) : (TSTEPS - 1);
        const float4 fz4 = *(const float4*)(pzp + (size_t)df * NPAD);
        const float fl0 = *(plp + (size_t)df * NPAD);

        // ---- Phase G: gate dots complete in zA..zD; all lane-local ----
        const float ia = actf(zA, -T2E, 0.f, 2.f, -1.f);
        const float ig = actf(zB, -L2E, 0.f, 1.f, 0.f);
        const float fg = actf(zC, -L2E, -L2E, 1.f, 0.f);   // sigmoid(z+1)
        const float og = actf(zD, -L2E, 0.f, 1.f, 0.f);
        cc = fmaf(cc, fg, ia * ig);
        const float hv = actf(cc, -T2E, 0.f, 2.f, -1.f) * og;

        // broadcast LSTM h, inter segment first (L0 is on the critical path)
#pragma unroll
        for (int k = 0; k < 18; k++) h[k] = rl(hv, k);

        // ---- Phase L0: 54 dots (len 18), 4-way split ----
        float A0 = curl0, A1 = 0.f, A2 = 0.f, A3 = 0.f;
#pragma unroll
        for (int k = 0; k < 16; k += 4) {
            A0 = fmaf(w0[k],     h[k],     A0);
            A1 = fmaf(w0[k + 1], h[k + 1], A1);
            A2 = fmaf(w0[k + 2], h[k + 2], A2);
            A3 = fmaf(w0[k + 3], h[k + 3], A3);
        }
        A0 = fmaf(w0[16], h[16], A0);
        A1 = fmaf(w0[17], h[17], A1);
        const float l0 = (A0 + A1) + (A2 + A3);

        // off-path: rest of hv broadcast + L1/L2 LSTM-h partial dots
#pragma unroll
        for (int k = 18; k < 33; k++) h[k] = rl(hv, k);
        float l1p = bias1;
#pragma unroll
        for (int k = 18; k < 30; k++) l1p = fmaf(w1[k], h[k], l1p);
        float l2p = bias2;
        l2p = fmaf(w2[12], h[30], l2p);
        l2p = fmaf(w2[13], h[31], l2p);
        l2p = fmaf(w2[14], h[32], l2p);

        // L0 combine
        {
            const float av = actf(l0, s0, 0.f, a0c, b0c);
            const float f1 = bperm(x0f1, av);
            const float f2 = bperm(x0f2, av);
            const float ti = bperm(x0ti, av);
            const float h0 = fmaf(ti, f2 - f1, f1);   // valid lanes 0..17
#pragma unroll
            for (int k = 0; k < 18; k++) h[k] = rl(h0, k);
        }

        // ---- seed next-step gates: inter segment (off path) ----
        zA = nz4.x; zB = nz4.y; zC = nz4.z; zD = nz4.w;
#pragma unroll
        for (int k = 0; k < 18; k++) {
            const float4 g4 = G4[k * 33 + iG];
            zA = fmaf(g4.x, h[k], zA);
            zB = fmaf(g4.y, h[k], zB);
            zC = fmaf(g4.z, h[k], zC);
            zD = fmaf(g4.w, h[k], zD);
        }

        // ---- Phase L1 residual: 18 terms over L0out, 4-way ----
        float B0 = l1p, B1 = 0.f, B2 = 0.f, B3 = 0.f;
#pragma unroll
        for (int k = 0; k < 16; k += 4) {
            B0 = fmaf(w1[k],     h[k],     B0);
            B1 = fmaf(w1[k + 1], h[k + 1], B1);
            B2 = fmaf(w1[k + 2], h[k + 2], B2);
            B3 = fmaf(w1[k + 3], h[k + 3], B3);
        }
        B0 = fmaf(w1[16], h[16], B0);
        B1 = fmaf(w1[17], h[17], B1);
        const float l1 = (B0 + B1) + (B2 + B3);
        {
            const float av = actf(l1, s1, 0.f, a1c, b1c);
            const float f1 = bperm(x1f1, av);
            const float f2 = bperm(x1f2, av);
            const float ti = bperm(x1ti, av);
            const float h1 = fmaf(ti, f2 - f1, f1);   // valid lanes 0..11
#pragma unroll
            for (int k = 0; k < 12; k++) h[18 + k] = rl(h1, k);
        }

        // ---- seed gates: command segment (off path) ----
#pragma unroll
        for (int k = 18; k < 30; k++) {
            const float4 g4 = G4[k * 33 + iG];
            zA = fmaf(g4.x, h[k], zA);
            zB = fmaf(g4.y, h[k], zB);
            zC = fmaf(g4.z, h[k], zC);
            zD = fmaf(g4.w, h[k], zD);
        }

        // ---- Phase L2 residual: 12 terms over L1out, 4-way ----
        float C0 = l2p, C1 = 0.f, C2 = 0.f, C3 = 0.f;
#pragma unroll
        for (int k = 0; k < 12; k += 4) {
            C0 = fmaf(w2[k],     h[18 + k],     C0);
            C1 = fmaf(w2[k + 1], h[18 + k + 1], C1);
            C2 = fmaf(w2[k + 2], h[18 + k + 2], C2);
            C3 = fmaf(w2[k + 3], h[18 + k + 3], C3);
        }
        const float l2 = (C0 + C1) + (C2 + C3);
        {
            const float av = actf(l2, s2, 0.f, a2c, b2c);
            const float f1 = bperm(x2f1, av);
            const float f2 = bperm(x2f2, av);
            const float ti = bperm(x2ti, av);
            const float h2 = fmaf(ti, f2 - f1, f1);   // valid lanes 0..2
            if (L < 3) outp[(size_t)t * 3] = h2;
            h[30] = rl(h2, 0); h[31] = rl(h2, 1); h[32] = rl(h2, 2);
        }

        // ---- seed gates: motor segment (trailing) ----
#pragma unroll
        for (int k = 30; k < 33; k++) {
            const float4 g4 = G4[k * 33 + iG];
            zA = fmaf(g4.x, h[k], zA);
            zB = fmaf(g4.y, h[k], zB);
            zC = fmaf(g4.z, h[k], zC);
            zD = fmaf(g4.w, h[k], zD);
        }

        // rotate prefetch pipeline
        curl0 = nl0;
        nz4 = fz4; nl0 = fl0;
    }
}

// ---------------------------------------------------------------------------
extern "C" void kernel_launch(void* const* d_in, const int* in_sizes, int n_in,
                              void* d_out, int out_size, void* d_ws, size_t ws_size,
                              hipStream_t stream) {
    const float* x       = (const float*)d_in[0];
    const float* fc1_w   = (const float*)d_in[1];
    const float* fc1_b   = (const float*)d_in[2];
    const float* lstm_wi = (const float*)d_in[3];
    const float* lstm_bi = (const float*)d_in[4];
    const float* lstm_wh = (const float*)d_in[5];
    const float* ff1w0 = (const float*)d_in[6];
    const float* ff2w0 = (const float*)d_in[7];
    const float* taw0  = (const float*)d_in[8];
    const float* tbw0  = (const float*)d_in[9];
    const float* ff1b0 = (const float*)d_in[10];
    const float* ff2b0 = (const float*)d_in[11];
    const float* tab0  = (const float*)d_in[12];
    const float* tbb0  = (const float*)d_in[13];
    const float* ff1w1 = (const float*)d_in[14];
    const float* ff2w1 = (const float*)d_in[15];
    const float* taw1  = (const float*)d_in[16];
    const float* tbw1  = (const float*)d_in[17];
    const float* ff1b1 = (const float*)d_in[18];
    const float* ff2b1 = (const float*)d_in[19];
    const float* tab1  = (const float*)d_in[20];
    const float* tbb1  = (const float*)d_in[21];
    const float* ff1w2 = (const float*)d_in[22];
    const float* ff2w2 = (const float*)d_in[23];
    const float* taw2  = (const float*)d_in[24];
    const float* tbw2  = (const float*)d_in[25];
    const float* ff1b2 = (const float*)d_in[26];
    const float* ff2b2 = (const float*)d_in[27];
    const float* tab2  = (const float*)d_in[28];
    const float* tbb2  = (const float*)d_in[29];
    const float* mask0 = (const float*)d_in[30];
    const float* mask1 = (const float*)d_in[31];
    const float* mask2 = (const float*)d_in[32];

    float* Wc = (float*)d_ws;            // 512*192 floats
    float* bc = Wc + 512 * NW;           // 192 floats
    float* P  = bc + NW;                 // 32768*192 floats (~25.2 MB)
    float* outp = (float*)d_out;

    fold_kernel<<<192, 256, 0, stream>>>(fc1_w, fc1_b, lstm_wi, lstm_bi,
                                         ff1w0, ff2w0, taw0, tbw0,
                                         ff1b0, ff2b0, tab0, tbb0, mask0, Wc, bc);
    gemm_kernel<<<dim3(BT / 64, 3), 256, 0, stream>>>(x, Wc, bc, P);
    scan_kernel<<<NBATCH, 64, 0, stream>>>(P, lstm_wh,
                                           ff1w0, ff2w0, taw0, tbw0,
                                           ff1w1, ff2w1, taw1, tbw1,
                                           ff1b1, ff2b1, tab1, tbb1,
                                           ff1w2, ff2w2, taw2, tbw2,
                                           ff1b2, ff2b2, tab2, tbb2,
                                           mask1, mask2, outp);
}

// Round 9
// 603.446 us; speedup vs baseline: 1.2750x; 1.0193x over previous
//
#include <hip/hip_runtime.h>
#include <hip/hip_bf16.h>

// Problem constants
#define BT 32768      // B*T = 64*512
#define TSTEPS 512
#define NBATCH 64
#define KDIM 512      // IN_DIM
#define NPAD 192      // P row stride
#define NW 192        // Wc cols

#define L2E 1.4426950408889634f
#define T2E 2.8853900817779268f

__device__ __forceinline__ float rl(float v, int lane) {
    return __int_as_float(__builtin_amdgcn_readlane(__float_as_int(v), lane));
}
__device__ __forceinline__ float bperm(int byteidx, float v) {
    return __int_as_float(__builtin_amdgcn_ds_bpermute(byteidx, __float_as_int(v)));
}
// unified activation: a * rcp(1 + exp2(s*x + sc)) + b
__device__ __forceinline__ float actf(float x, float s, float sc, float a, float b) {
    float e = exp2f(fmaf(s, x, sc));
    return fmaf(a, __builtin_amdgcn_rcpf(1.f + e), b);
}

// P column layout (scan-friendly):
//   z dot (gate g, neuron i) -> col 4*i+g   (cols 0..131; lane i reads float4 @ 4i)
//   L0 dot e -> col 132+e                   (cols 132..185; lane 4+e reads scalar)
//   cols 186..191 pad (zero)
__device__ __forceinline__ int permpos(int o) {
    if (o < 132) { int g = o / 33, i = o - g * 33; return 4 * i + g; }
    return o;
}

// ---------------------------------------------------------------------------
// Kernel 1: fold fc1 into the stacked scan-input projection (permuted cols).
// ---------------------------------------------------------------------------
__global__ __launch_bounds__(256) void fold_kernel(
    const float* __restrict__ fc1_w, const float* __restrict__ fc1_b,
    const float* __restrict__ lstm_wi, const float* __restrict__ lstm_bi,
    const float* __restrict__ ff1w0, const float* __restrict__ ff2w0,
    const float* __restrict__ taw0, const float* __restrict__ tbw0,
    const float* __restrict__ ff1b0, const float* __restrict__ ff2b0,
    const float* __restrict__ tab0, const float* __restrict__ tbb0,
    const float* __restrict__ mask0,
    float* __restrict__ Wc, float* __restrict__ bc)
{
    const int o = blockIdx.x;   // 0..191 logical column
    const int t = threadIdx.x;  // 0..255 = latent index l
    const int p = permpos(o);
    __shared__ float wrow[256];
    __shared__ float red[256];

    float wl = 0.f, b0 = 0.f;
    if (o < 132) { wl = lstm_wi[o * 256 + t]; b0 = lstm_bi[o]; }
    else if (o < 186) {
        const int e = o - 132, m = e / 18, i = e - m * 18;
        if (m == 0)      { wl = ff1w0[i * 274 + t] * mask0[i * 274 + t]; b0 = ff1b0[i]; }
        else if (m == 1) { wl = ff2w0[i * 274 + t] * mask0[i * 274 + t]; b0 = ff2b0[i]; }
        else             { wl = taw0[i * 274 + t] + tbw0[i * 274 + t];   b0 = tab0[i] + tbb0[i]; }
    }
    wrow[t] = wl;
    __syncthreads();

    float acc0 = 0.f, acc1 = 0.f;
    for (int l = 0; l < 256; l++) {
        float w = wrow[l];
        acc0 = fmaf(fc1_w[l * 512 + t], w, acc0);
        acc1 = fmaf(fc1_w[l * 512 + t + 256], w, acc1);
    }
    Wc[(size_t)t * NW + p] = acc0;
    Wc[(size_t)(t + 256) * NW + p] = acc1;

    red[t] = fc1_b[t] * wl;
    __syncthreads();
    for (int s = 128; s > 0; s >>= 1) {
        if (t < s) red[t] += red[t + s];
        __syncthreads();
    }
    if (t == 0) bc[p] = red[0] + b0;
}

// ---------------------------------------------------------------------------
// Kernel 2: P[m][n] = sum_k X[m][k]*Wc[k][n] + bc[n], fp32 LDS-tiled GEMM.
// M=32768, K=512, N=192. Tile 128x64x16, 8x4 acc/thread, grid (256, 3).
// Inner k: 32 FMAs per 3 ds_read_b128 (~89% FMA issue density).
// ---------------------------------------------------------------------------
__global__ __launch_bounds__(256) void gemm_kernel(
    const float* __restrict__ X, const float* __restrict__ Wc,
    const float* __restrict__ bc, float* __restrict__ P)
{
    __shared__ float As[16][128];   // [k][m]
    __shared__ float Bs[16][64];    // [k][n]
    const int tid = threadIdx.x;
    const int m0 = blockIdx.x * 128;
    const int n0 = blockIdx.y * 64;
    // A loader: row lr, k-cols lc..lc+7 (2 float4 from one row, coalesced pairs)
    const int lr = tid >> 1;             // 0..127
    const int lc = (tid & 1) << 3;       // 0 or 8
    // B loader: 16x64 floats, 1 float4/thread
    const int bk = tid >> 4;             // 0..15
    const int bn = (tid & 15) << 2;      // 0..60
    // compute mapping: 8 rows x 4 cols per thread
    const int tm = (tid & 15) << 3;      // 0..120
    const int tn = (tid >> 4) << 2;      // 0..60

    float acc[8][4];
#pragma unroll
    for (int i = 0; i < 8; i++)
#pragma unroll
        for (int j = 0; j < 4; j++) acc[i][j] = 0.f;

    const float* xp = X + (size_t)(m0 + lr) * KDIM + lc;

    for (int k0 = 0; k0 < KDIM; k0 += 16) {
        const float4 a0 = *(const float4*)(xp + k0);
        const float4 a1 = *(const float4*)(xp + k0 + 4);
        const float4 bv = *(const float4*)(Wc + (size_t)(k0 + bk) * NW + n0 + bn);
        __syncthreads();
        As[lc + 0][lr] = a0.x; As[lc + 1][lr] = a0.y;
        As[lc + 2][lr] = a0.z; As[lc + 3][lr] = a0.w;
        As[lc + 4][lr] = a1.x; As[lc + 5][lr] = a1.y;
        As[lc + 6][lr] = a1.z; As[lc + 7][lr] = a1.w;
        *(float4*)&Bs[bk][bn] = bv;
        __syncthreads();
#pragma unroll
        for (int k = 0; k < 16; k++) {
            const float4 b = *(const float4*)&Bs[k][tn];
            const float4 x0 = *(const float4*)&As[k][tm];
            const float4 x1 = *(const float4*)&As[k][tm + 4];
            acc[0][0] = fmaf(x0.x, b.x, acc[0][0]); acc[0][1] = fmaf(x0.x, b.y, acc[0][1]);
            acc[0][2] = fmaf(x0.x, b.z, acc[0][2]); acc[0][3] = fmaf(x0.x, b.w, acc[0][3]);
            acc[1][0] = fmaf(x0.y, b.x, acc[1][0]); acc[1][1] = fmaf(x0.y, b.y, acc[1][1]);
            acc[1][2] = fmaf(x0.y, b.z, acc[1][2]); acc[1][3] = fmaf(x0.y, b.w, acc[1][3]);
            acc[2][0] = fmaf(x0.z, b.x, acc[2][0]); acc[2][1] = fmaf(x0.z, b.y, acc[2][1]);
            acc[2][2] = fmaf(x0.z, b.z, acc[2][2]); acc[2][3] = fmaf(x0.z, b.w, acc[2][3]);
            acc[3][0] = fmaf(x0.w, b.x, acc[3][0]); acc[3][1] = fmaf(x0.w, b.y, acc[3][1]);
            acc[3][2] = fmaf(x0.w, b.z, acc[3][2]); acc[3][3] = fmaf(x0.w, b.w, acc[3][3]);
            acc[4][0] = fmaf(x1.x, b.x, acc[4][0]); acc[4][1] = fmaf(x1.x, b.y, acc[4][1]);
            acc[4][2] = fmaf(x1.x, b.z, acc[4][2]); acc[4][3] = fmaf(x1.x, b.w, acc[4][3]);
            acc[5][0] = fmaf(x1.y, b.x, acc[5][0]); acc[5][1] = fmaf(x1.y, b.y, acc[5][1]);
            acc[5][2] = fmaf(x1.y, b.z, acc[5][2]); acc[5][3] = fmaf(x1.y, b.w, acc[5][3]);
            acc[6][0] = fmaf(x1.z, b.x, acc[6][0]); acc[6][1] = fmaf(x1.z, b.y, acc[6][1]);
            acc[6][2] = fmaf(x1.z, b.z, acc[6][2]); acc[6][3] = fmaf(x1.z, b.w, acc[6][3]);
            acc[7][0] = fmaf(x1.w, b.x, acc[7][0]); acc[7][1] = fmaf(x1.w, b.y, acc[7][1]);
            acc[7][2] = fmaf(x1.w, b.z, acc[7][2]); acc[7][3] = fmaf(x1.w, b.w, acc[7][3]);
        }
    }

    {
        const float4 bias = *(const float4*)(bc + n0 + tn);
#pragma unroll
        for (int i = 0; i < 8; i++) {
            float4 r;
            r.x = acc[i][0] + bias.x; r.y = acc[i][1] + bias.y;
            r.z = acc[i][2] + bias.z; r.w = acc[i][3] + bias.w;
            *(float4*)(P + (size_t)(m0 + tm + i) * NPAD + n0 + tn) = r;
        }
    }
}

// ---------------------------------------------------------------------------
// Kernel 3: persistent scan, one wave per batch element.  (unchanged from R8)
// ---------------------------------------------------------------------------
__global__ __launch_bounds__(64)
__attribute__((amdgpu_waves_per_eu(1, 1)))
void scan_kernel(
    const float* __restrict__ P, const float* __restrict__ lstm_wh,
    const float* __restrict__ ff1w0, const float* __restrict__ ff2w0,
    const float* __restrict__ taw0, const float* __restrict__ tbw0,
    const float* __restrict__ ff1w1, const float* __restrict__ ff2w1,
    const float* __restrict__ taw1, const float* __restrict__ tbw1,
    const float* __restrict__ ff1b1, const float* __restrict__ ff2b1,
    const float* __restrict__ tab1, const float* __restrict__ tbb1,
    const float* __restrict__ ff1w2, const float* __restrict__ ff2w2,
    const float* __restrict__ taw2, const float* __restrict__ tbw2,
    const float* __restrict__ ff1b2, const float* __restrict__ ff2b2,
    const float* __restrict__ tab2, const float* __restrict__ tbb2,
    const float* __restrict__ mask1, const float* __restrict__ mask2,
    float* __restrict__ out)
{
    const int L = threadIdx.x;
    const int b = blockIdx.x;

    // packed gate weights: G4[k*33+i] = (w_ia, w_ig, w_fg, w_og) for neuron i, term k
    __shared__ float4 G4[33 * 33];
    for (int idx = L; idx < 33 * 33; idx += 64) {
        const int k = idx / 33, i = idx - k * 33;
        float4 g;
        g.x = lstm_wh[i * 33 + k];
        g.y = lstm_wh[(33 + i) * 33 + k];
        g.z = lstm_wh[(66 + i) * 33 + k];
        g.w = lstm_wh[(99 + i) * 33 + k];
        G4[idx] = g;
    }
    __syncthreads();

    const int iG = (L < 33) ? L : 32;   // gate neuron (lanes 33..63 duplicate 32)

    // ---- L0 weights: dot e=L-4 (clamped), m=e/18; ta+tb merged ----
    float w0[18];
    {
        int e = L - 4; e = (e < 0) ? 0 : ((e > 53) ? 53 : e);
        const int m = e / 18, i = e - m * 18;
        const float* pa = (m == 0) ? ff1w0 : (m == 1) ? ff2w0 : taw0;
#pragma unroll
        for (int k = 0; k < 18; k++) {
            float w = pa[i * 274 + 256 + k];
            if (m == 2) w += tbw0[i * 274 + 256 + k];
            w0[k] = w;
        }
    }
    // ---- L1 weights: dot d=m*12+i on lanes 0..35 ----
    float w1[30], bias1;
    {
        const int d = (L < 36) ? L : 35;
        const int m = d / 12, i = d - m * 12;
        const float* pa = (m == 0) ? ff1w1 : (m == 1) ? ff2w1 : taw1;
#pragma unroll
        for (int k = 0; k < 30; k++) {
            float w = pa[i * 30 + k];
            if (m == 2) w += tbw1[i * 30 + k];
            else w *= mask1[i * 30 + k];
            w1[k] = w;
        }
        bias1 = (m == 0) ? ff1b1[i] : (m == 1) ? ff2b1[i] : (tab1[i] + tbb1[i]);
    }
    // ---- L2 weights: dot d=m*3+i on lanes 0..8 ----
    float w2[15], bias2;
    {
        const int d = (L < 9) ? L : 8;
        const int m = d / 3, i = d - m * 3;
        const float* pa = (m == 0) ? ff1w2 : (m == 1) ? ff2w2 : taw2;
#pragma unroll
        for (int k = 0; k < 15; k++) {
            float w = pa[i * 15 + k];
            if (m == 2) w += tbw2[i * 15 + k];
            else w *= mask2[i * 15 + k];
            w2[k] = w;
        }
        bias2 = (m == 0) ? ff1b2[i] : (m == 1) ? ff2b2[i] : (tab2[i] + tbb2[i]);
    }

    // ---- per-lane activation constants (layers only) ----
    const float s0  = (L < 40) ? -T2E : -L2E;   // L0: lanes 4..39 tanh, 40..57 sig
    const float a0c = (L < 40) ? 2.f : 1.f;
    const float b0c = (L < 40) ? -1.f : 0.f;
    const float s1  = (L < 24) ? -T2E : -L2E;
    const float a1c = (L < 24) ? 2.f : 1.f;
    const float b1c = (L < 24) ? -1.f : 0.f;
    const float s2  = (L < 6) ? -T2E : -L2E;
    const float a2c = (L < 6) ? 2.f : 1.f;
    const float b2c = (L < 6) ? -1.f : 0.f;

    // ---- per-lane bpermute byte indices (layer combines) ----
    const int x0f1 = (4 * (4 + L)) & 255;
    const int x0f2 = (4 * (22 + L)) & 255;
    const int x0ti = (4 * (40 + L)) & 255;
    const int x1f1 = (4 * L) & 255;
    const int x1f2 = (4 * (12 + L)) & 255;
    const int x1ti = (4 * (24 + L)) & 255;
    const int x2f1 = (4 * L) & 255;
    const int x2f2 = (4 * (3 + L)) & 255;
    const int x2ti = (4 * (6 + L)) & 255;

    // ---- state ----
    float h[33];
#pragma unroll
    for (int k = 0; k < 33; k++) h[k] = 0.f;
    float cc = 0.f;

    // per-lane P addresses: z float4 @ col 4*iG; L0 scalar @ col 128+clamp(L,4,57)
    const float* Pb = P + (size_t)b * TSTEPS * NPAD;
    int Lc = L; if (Lc < 4) Lc = 4; if (Lc > 57) Lc = 57;
    const float* pzp = Pb + 4 * iG;
    const float* plp = Pb + 128 + Lc;

    // step-0 seeds (carry = 0 -> pure precomp) and step-0 L0 precomp
    float4 z0 = *(const float4*)pzp;
    float zA = z0.x, zB = z0.y, zC = z0.z, zD = z0.w;
    float curl0 = *plp;
    // prefetch step-1
    float4 nz4 = *(const float4*)(pzp + NPAD);
    float nl0 = *(plp + NPAD);

    float* outp = out + (size_t)b * TSTEPS * 3 + L;

#pragma unroll 1
    for (int t = 0; t < TSTEPS; t++) {
        // issue loads for step t+2
        const int df = (t + 2 < TSTEPS) ? (t + 2) : (TSTEPS - 1);
        const float4 fz4 = *(const float4*)(pzp + (size_t)df * NPAD);
        const float fl0 = *(plp + (size_t)df * NPAD);

        // ---- Phase G: gate dots complete in zA..zD; all lane-local ----
        const float ia = actf(zA, -T2E, 0.f, 2.f, -1.f);
        const float ig = actf(zB, -L2E, 0.f, 1.f, 0.f);
        const float fg = actf(zC, -L2E, -L2E, 1.f, 0.f);   // sigmoid(z+1)
        const float og = actf(zD, -L2E, 0.f, 1.f, 0.f);
        cc = fmaf(cc, fg, ia * ig);
        const float hv = actf(cc, -T2E, 0.f, 2.f, -1.f) * og;

        // broadcast LSTM h, inter segment first (L0 is on the critical path)
#pragma unroll
        for (int k = 0; k < 18; k++) h[k] = rl(hv, k);

        // ---- Phase L0: 54 dots (len 18), 4-way split ----
        float A0 = curl0, A1 = 0.f, A2 = 0.f, A3 = 0.f;
#pragma unroll
        for (int k = 0; k < 16; k += 4) {
            A0 = fmaf(w0[k],     h[k],     A0);
            A1 = fmaf(w0[k + 1], h[k + 1], A1);
            A2 = fmaf(w0[k + 2], h[k + 2], A2);
            A3 = fmaf(w0[k + 3], h[k + 3], A3);
        }
        A0 = fmaf(w0[16], h[16], A0);
        A1 = fmaf(w0[17], h[17], A1);
        const float l0 = (A0 + A1) + (A2 + A3);

        // off-path: rest of hv broadcast + L1/L2 LSTM-h partial dots
#pragma unroll
        for (int k = 18; k < 33; k++) h[k] = rl(hv, k);
        float l1p = bias1;
#pragma unroll
        for (int k = 18; k < 30; k++) l1p = fmaf(w1[k], h[k], l1p);
        float l2p = bias2;
        l2p = fmaf(w2[12], h[30], l2p);
        l2p = fmaf(w2[13], h[31], l2p);
        l2p = fmaf(w2[14], h[32], l2p);

        // L0 combine
        {
            const float av = actf(l0, s0, 0.f, a0c, b0c);
            const float f1 = bperm(x0f1, av);
            const float f2 = bperm(x0f2, av);
            const float ti = bperm(x0ti, av);
            const float h0 = fmaf(ti, f2 - f1, f1);   // valid lanes 0..17
#pragma unroll
            for (int k = 0; k < 18; k++) h[k] = rl(h0, k);
        }

        // ---- seed next-step gates: inter segment (off path) ----
        zA = nz4.x; zB = nz4.y; zC = nz4.z; zD = nz4.w;
#pragma unroll
        for (int k = 0; k < 18; k++) {
            const float4 g4 = G4[k * 33 + iG];
            zA = fmaf(g4.x, h[k], zA);
            zB = fmaf(g4.y, h[k], zB);
            zC = fmaf(g4.z, h[k], zC);
            zD = fmaf(g4.w, h[k], zD);
        }

        // ---- Phase L1 residual: 18 terms over L0out, 4-way ----
        float B0 = l1p, B1 = 0.f, B2 = 0.f, B3 = 0.f;
#pragma unroll
        for (int k = 0; k < 16; k += 4) {
            B0 = fmaf(w1[k],     h[k],     B0);
            B1 = fmaf(w1[k + 1], h[k + 1], B1);
            B2 = fmaf(w1[k + 2], h[k + 2], B2);
            B3 = fmaf(w1[k + 3], h[k + 3], B3);
        }
        B0 = fmaf(w1[16], h[16], B0);
        B1 = fmaf(w1[17], h[17], B1);
        const float l1 = (B0 + B1) + (B2 + B3);
        {
            const float av = actf(l1, s1, 0.f, a1c, b1c);
            const float f1 = bperm(x1f1, av);
            const float f2 = bperm(x1f2, av);
            const float ti = bperm(x1ti, av);
            const float h1 = fmaf(ti, f2 - f1, f1);   // valid lanes 0..11
#pragma unroll
            for (int k = 0; k < 12; k++) h[18 + k] = rl(h1, k);
        }

        // ---- seed gates: command segment (off path) ----
#pragma unroll
        for (int k = 18; k < 30; k++) {
            const float4 g4 = G4[k * 33 + iG];
            zA = fmaf(g4.x, h[k], zA);
            zB = fmaf(g4.y, h[k], zB);
            zC = fmaf(g4.z, h[k], zC);
            zD = fmaf(g4.w, h[k], zD);
        }

        // ---- Phase L2 residual: 12 terms over L1out, 4-way ----
        float C0 = l2p, C1 = 0.f, C2 = 0.f, C3 = 0.f;
#pragma unroll
        for (int k = 0; k < 12; k += 4) {
            C0 = fmaf(w2[k],     h[18 + k],     C0);
            C1 = fmaf(w2[k + 1], h[18 + k + 1], C1);
            C2 = fmaf(w2[k + 2], h[18 + k + 2], C2);
            C3 = fmaf(w2[k + 3], h[18 + k + 3], C3);
        }
        const float l2 = (C0 + C1) + (C2 + C3);
        {
            const float av = actf(l2, s2, 0.f, a2c, b2c);
            const float f1 = bperm(x2f1, av);
            const float f2 = bperm(x2f2, av);
            const float ti = bperm(x2ti, av);
            const float h2 = fmaf(ti, f2 - f1, f1);   // valid lanes 0..2
            if (L < 3) outp[(size_t)t * 3] = h2;
            h[30] = rl(h2, 0); h[31] = rl(h2, 1); h[32] = rl(h2, 2);
        }

        // ---- seed gates: motor segment (trailing) ----
#pragma unroll
        for (int k = 30; k < 33; k++) {
            const float4 g4 = G4[k * 33 + iG];
            zA = fmaf(g4.x, h[k], zA);
            zB = fmaf(g4.y, h[k], zB);
            zC = fmaf(g4.z, h[k], zC);
            zD = fmaf(g4.w, h[k], zD);
        }

        // rotate prefetch pipeline
        curl0 = nl0;
        nz4 = fz4; nl0 = fl0;
    }
}

// ---------------------------------------------------------------------------
extern "C" void kernel_launch(void* const* d_in, const int* in_sizes, int n_in,
                              void* d_out, int out_size, void* d_ws, size_t ws_size,
                              hipStream_t stream) {
    const float* x       = (const float*)d_in[0];
    const float* fc1_w   = (const float*)d_in[1];
    const float* fc1_b   = (const float*)d_in[2];
    const float* lstm_wi = (const float*)d_in[3];
    const float* lstm_bi = (const float*)d_in[4];
    const float* lstm_wh = (const float*)d_in[5];
    const float* ff1w0 = (const float*)d_in[6];
    const float* ff2w0 = (const float*)d_in[7];
    const float* taw0  = (const float*)d_in[8];
    const float* tbw0  = (const float*)d_in[9];
    const float* ff1b0 = (const float*)d_in[10];
    const float* ff2b0 = (const float*)d_in[11];
    const float* tab0  = (const float*)d_in[12];
    const float* tbb0  = (const float*)d_in[13];
    const float* ff1w1 = (const float*)d_in[14];
    const float* ff2w1 = (const float*)d_in[15];
    const float* taw1  = (const float*)d_in[16];
    const float* tbw1  = (const float*)d_in[17];
    const float* ff1b1 = (const float*)d_in[18];
    const float* ff2b1 = (const float*)d_in[19];
    const float* tab1  = (const float*)d_in[20];
    const float* tbb1  = (const float*)d_in[21];
    const float* ff1w2 = (const float*)d_in[22];
    const float* ff2w2 = (const float*)d_in[23];
    const float* taw2  = (const float*)d_in[24];
    const float* tbw2  = (const float*)d_in[25];
    const float* ff1b2 = (const float*)d_in[26];
    const float* ff2b2 = (const float*)d_in[27];
    const float* tab2  = (const float*)d_in[28];
    const float* tbb2  = (const float*)d_in[29];
    const float* mask0 = (const float*)d_in[30];
    const float* mask1 = (const float*)d_in[31];
    const float* mask2 = (const float*)d_in[32];

    float* Wc = (float*)d_ws;            // 512*192 floats
    float* bc = Wc + 512 * NW;           // 192 floats
    float* P  = bc + NW;                 // 32768*192 floats (~25.2 MB)
    float* outp = (float*)d_out;

    fold_kernel<<<192, 256, 0, stream>>>(fc1_w, fc1_b, lstm_wi, lstm_bi,
                                         ff1w0, ff2w0, taw0, tbw0,
                                         ff1b0, ff2b0, tab0, tbb0, mask0, Wc, bc);
    gemm_kernel<<<dim3(BT / 128, 3), 256, 0, stream>>>(x, Wc, bc, P);
    scan_kernel<<<NBATCH, 64, 0, stream>>>(P, lstm_wh,
                                           ff1w0, ff2w0, taw0, tbw0,
                                           ff1w1, ff2w1, taw1, tbw1,
                                           ff1b1, ff2b1, tab1, tbb1,
                                           ff1w2, ff2w2, taw2, tbw2,
                                           ff1b2, ff2b2, tab2, tbb2,
                                           mask1, mask2, outp);
}